// Round 2
// baseline (2007.353 us; speedup 1.0000x reference)
//
#include <hip/hip_runtime.h>
#include <math.h>

#define NN 8192
#define DD 14
#define DP 16
#define FF 2048
#define HID 256
#define LN_EPS 1e-5f
#define NCH 64      // attention key chunks
#define CHK 128     // keys per chunk
#define FCH 32      // ffn j per chunk
#define NFCH 64     // ffn chunks
#define QSCALE (1.4426950408889634f / 3.7416573867739413f)  // log2(e)/sqrt(14)

#define LOAD16(dst, srcp) { \
  const float4* _p = (const float4*)(srcp); \
  float4 _a = _p[0], _b = _p[1], _c = _p[2], _d = _p[3]; \
  dst[0]=_a.x; dst[1]=_a.y; dst[2]=_a.z; dst[3]=_a.w; \
  dst[4]=_b.x; dst[5]=_b.y; dst[6]=_b.z; dst[7]=_b.w; \
  dst[8]=_c.x; dst[9]=_c.y; dst[10]=_c.z; dst[11]=_c.w; \
  dst[12]=_d.x; dst[13]=_d.y; dst[14]=_d.z; dst[15]=_d.w; }

#define STORE16(dstp, src) { \
  float4* _p = (float4*)(dstp); \
  _p[0] = make_float4(src[0], src[1], src[2], src[3]); \
  _p[1] = make_float4(src[4], src[5], src[6], src[7]); \
  _p[2] = make_float4(src[8], src[9], src[10], src[11]); \
  _p[3] = make_float4(src[12], src[13], src[14], src[15]); }

static __device__ __forceinline__ float fast_exp2(float x) {
#if __has_builtin(__builtin_amdgcn_exp2f)
  return __builtin_amdgcn_exp2f(x);
#else
  return exp2f(x);
#endif
}

// ---------------- copy x -> padded h ----------------
__global__ void copy_x(const float* __restrict__ x, float* __restrict__ h) {
  int r = blockIdx.x * 256 + threadIdx.x;
  float v[16];
  #pragma unroll
  for (int d = 0; d < 14; d++) v[d] = x[(size_t)r * 14 + d];
  v[14] = 0.f; v[15] = 0.f;
  STORE16(h + (size_t)r * DP, v);
}

// ---------------- qkv projection (+ zero attn accumulator) ----------------
__global__ void qkv_proj(const float* __restrict__ h, const float* __restrict__ wqkv,
                         const float* __restrict__ bqkv, float* __restrict__ Q,
                         float* __restrict__ K, float* __restrict__ V,
                         float* __restrict__ aacc) {
  int r = blockIdx.x * 256 + threadIdx.x;
  float hr[16];
  LOAD16(hr, h + (size_t)r * DP);
  #pragma unroll 6
  for (int c = 0; c < 42; c++) {
    const float* w = wqkv + c * 14;
    float s = bqkv[c];
    #pragma unroll
    for (int d = 0; d < 14; d++) s = fmaf(hr[d], w[d], s);
    if (c < 14)       Q[(size_t)r * DP + c]        = s * QSCALE;
    else if (c < 28)  K[(size_t)r * DP + (c - 14)] = s;
    else              V[(size_t)r * DP + (c - 28)] = s;
  }
  Q[(size_t)r * DP + 14] = 0.f; Q[(size_t)r * DP + 15] = 0.f;
  K[(size_t)r * DP + 14] = 0.f; K[(size_t)r * DP + 15] = 0.f;
  V[(size_t)r * DP + 14] = 0.f; V[(size_t)r * DP + 15] = 0.f;
  float z[16];
  #pragma unroll
  for (int d = 0; d < 16; d++) z[d] = 0.f;
  STORE16(aacc + (size_t)r * 16, z);
}

// ---------------- attention phase 1: no-max exp2, atomic combine ----------------
__global__ __launch_bounds__(256, 4) void attn_phase1(
    const float* __restrict__ Q, const float* __restrict__ Kb,
    const float* __restrict__ Vb, float* __restrict__ aacc) {
  __shared__ float Ks[CHK][DP];
  __shared__ float Vs[CHK][DP];
  const int tid = threadIdx.x;
  const int rowBase = blockIdx.x * 512;
  const int kBase = blockIdx.y * CHK;
  for (int idx = tid; idx < CHK * 4; idx += 256) {
    int j = idx >> 2, c = idx & 3;
    ((float4*)&Ks[j][0])[c] = ((const float4*)(Kb + (size_t)(kBase + j) * DP))[c];
    ((float4*)&Vs[j][0])[c] = ((const float4*)(Vb + (size_t)(kBase + j) * DP))[c];
  }
  __syncthreads();
  const int rA = rowBase + tid;
  const int rB = rA + 256;
  float qa[16], qb[16];
  LOAD16(qa, Q + (size_t)rA * DP);
  LOAD16(qb, Q + (size_t)rB * DP);
  float aA[14], aB[14];
  #pragma unroll
  for (int d = 0; d < 14; d++) { aA[d] = 0.f; aB[d] = 0.f; }
  float lA = 0.f, lB = 0.f;

  for (int j = 0; j < CHK; j++) {
    float kv[16];
    LOAD16(kv, &Ks[j][0]);
    float sA0=0.f,sA1=0.f,sA2=0.f,sA3=0.f,sB0=0.f,sB1=0.f,sB2=0.f,sB3=0.f;
    #pragma unroll
    for (int d = 0; d < 4; d++) {
      sA0 = fmaf(qa[d],      kv[d],      sA0);
      sA1 = fmaf(qa[d + 4],  kv[d + 4],  sA1);
      sA2 = fmaf(qa[d + 8],  kv[d + 8],  sA2);
      sA3 = fmaf(qa[d + 12], kv[d + 12], sA3);
      sB0 = fmaf(qb[d],      kv[d],      sB0);
      sB1 = fmaf(qb[d + 4],  kv[d + 4],  sB1);
      sB2 = fmaf(qb[d + 8],  kv[d + 8],  sB2);
      sB3 = fmaf(qb[d + 12], kv[d + 12], sB3);
    }
    float pA = fast_exp2((sA0 + sA1) + (sA2 + sA3));
    float pB = fast_exp2((sB0 + sB1) + (sB2 + sB3));
    float vv[16];
    LOAD16(vv, &Vs[j][0]);
    lA += pA;
    lB += pB;
    #pragma unroll
    for (int d = 0; d < 14; d++) {
      aA[d] = fmaf(pA, vv[d], aA[d]);
      aB[d] = fmaf(pB, vv[d], aB[d]);
    }
  }
  float* accA = aacc + (size_t)rA * 16;
  float* accB = aacc + (size_t)rB * 16;
  #pragma unroll
  for (int d = 0; d < 14; d++) {
    atomicAdd(accA + d, aA[d]);
    atomicAdd(accB + d, aB[d]);
  }
  atomicAdd(accA + 14, lA);
  atomicAdd(accB + 14, lB);
}

// ---- attention combine + out-proj + residual + LN1 (+ zero ffn accumulator) ----
__global__ void attn_combine_ln1(float* __restrict__ h, const float* __restrict__ aacc,
                                 const float* __restrict__ wo, const float* __restrict__ bo,
                                 const float* __restrict__ g, const float* __restrict__ b,
                                 float* __restrict__ facc) {
  int r = blockIdx.x * 256 + threadIdx.x;
  float p[16];
  LOAD16(p, aacc + (size_t)r * 16);
  float inv = 1.f / p[14];
  float a[14];
  #pragma unroll
  for (int d = 0; d < 14; d++) a[d] = p[d] * inv;
  float hr[16];
  LOAD16(hr, h + (size_t)r * DP);
  float xx[14];
  #pragma unroll
  for (int i = 0; i < 14; i++) {
    float s = bo[i];
    #pragma unroll
    for (int d = 0; d < 14; d++) s = fmaf(wo[i * 14 + d], a[d], s);
    xx[i] = hr[i] + s;
  }
  float mu = 0.f;
  #pragma unroll
  for (int i = 0; i < 14; i++) mu += xx[i];
  mu *= (1.f / 14.f);
  float var = 0.f;
  #pragma unroll
  for (int i = 0; i < 14; i++) { float t = xx[i] - mu; var = fmaf(t, t, var); }
  var *= (1.f / 14.f);
  float rs = rsqrtf(var + LN_EPS);
  float o[16];
  #pragma unroll
  for (int i = 0; i < 14; i++) o[i] = fmaf((xx[i] - mu) * rs, g[i], b[i]);
  o[14] = 0.f; o[15] = 0.f;
  STORE16(h + (size_t)r * DP, o);
  float z[16];
  #pragma unroll
  for (int d = 0; d < 16; d++) z[d] = 0.f;
  STORE16(facc + (size_t)r * 16, z);
}

// ---------------- fused FFN phase 1 (atomic partials over j-chunks) ----------------
__global__ __launch_bounds__(256, 4) void ffn_phase1(
    const float* __restrict__ h, const float* __restrict__ w1,
    const float* __restrict__ b1, const float* __restrict__ w2,
    float* __restrict__ facc) {
  __shared__ float W1s[FCH][16];
  __shared__ float W2s[FCH][16];
  __shared__ float b1s[FCH];
  const int tid = threadIdx.x;
  const int jbase = blockIdx.y * FCH;
  for (int idx = tid; idx < FCH * 16; idx += 256) {
    int j = idx >> 4, d = idx & 15;
    W1s[j][d] = (d < 14) ? w1[(size_t)(jbase + j) * 14 + d] : 0.f;
    W2s[j][d] = (d < 14) ? w2[(size_t)d * FF + jbase + j] : 0.f;
  }
  if (tid < FCH) b1s[tid] = b1[jbase + tid];
  __syncthreads();
  const int rA = blockIdx.x * 512 + tid;
  const int rB = rA + 256;
  float ha[16], hb[16];
  LOAD16(ha, h + (size_t)rA * DP);
  LOAD16(hb, h + (size_t)rB * DP);
  float aA[14], aB[14];
  #pragma unroll
  for (int d = 0; d < 14; d++) { aA[d] = 0.f; aB[d] = 0.f; }
  for (int j = 0; j < FCH; j++) {
    float w1v[16];
    LOAD16(w1v, &W1s[j][0]);
    float sA0=0.f,sA1=0.f,sA2=0.f,sA3=0.f,sB0=0.f,sB1=0.f,sB2=0.f,sB3=0.f;
    #pragma unroll
    for (int d = 0; d < 4; d++) {
      sA0 = fmaf(ha[d],      w1v[d],      sA0);
      sA1 = fmaf(ha[d + 4],  w1v[d + 4],  sA1);
      sA2 = fmaf(ha[d + 8],  w1v[d + 8],  sA2);
      sA3 = fmaf(ha[d + 12], w1v[d + 12], sA3);
      sB0 = fmaf(hb[d],      w1v[d],      sB0);
      sB1 = fmaf(hb[d + 4],  w1v[d + 4],  sB1);
      sB2 = fmaf(hb[d + 8],  w1v[d + 8],  sB2);
      sB3 = fmaf(hb[d + 12], w1v[d + 12], sB3);
    }
    float tA = fmaxf(((sA0 + sA1) + (sA2 + sA3)) + b1s[j], 0.f);
    float tB = fmaxf(((sB0 + sB1) + (sB2 + sB3)) + b1s[j], 0.f);
    float w2v[16];
    LOAD16(w2v, &W2s[j][0]);
    #pragma unroll
    for (int d = 0; d < 14; d++) {
      aA[d] = fmaf(tA, w2v[d], aA[d]);
      aB[d] = fmaf(tB, w2v[d], aB[d]);
    }
  }
  float* accA = facc + (size_t)rA * 16;
  float* accB = facc + (size_t)rB * 16;
  #pragma unroll
  for (int d = 0; d < 14; d++) {
    atomicAdd(accA + d, aA[d]);
    atomicAdd(accB + d, aB[d]);
  }
}

// ---------------- FFN combine + residual + LN2 ----------------
__global__ void ffn_combine_ln2(float* __restrict__ h, const float* __restrict__ facc,
                                const float* __restrict__ b2, const float* __restrict__ g,
                                const float* __restrict__ b) {
  int r = blockIdx.x * 256 + threadIdx.x;
  float p[16];
  LOAD16(p, facc + (size_t)r * 16);
  float hr[16];
  LOAD16(hr, h + (size_t)r * DP);
  float xx[14];
  #pragma unroll
  for (int i = 0; i < 14; i++) xx[i] = hr[i] + p[i] + b2[i];
  float mu = 0.f;
  #pragma unroll
  for (int i = 0; i < 14; i++) mu += xx[i];
  mu *= (1.f / 14.f);
  float var = 0.f;
  #pragma unroll
  for (int i = 0; i < 14; i++) { float t = xx[i] - mu; var = fmaf(t, t, var); }
  var *= (1.f / 14.f);
  float rs = rsqrtf(var + LN_EPS);
  float o[16];
  #pragma unroll
  for (int i = 0; i < 14; i++) o[i] = fmaf((xx[i] - mu) * rs, g[i], b[i]);
  o[14] = 0.f; o[15] = 0.f;
  STORE16(h + (size_t)r * DP, o);
}

// ---------------- size head: fc1 -> fc2 -> size_out ----------------
__global__ void head_size(const float* __restrict__ h, const float* __restrict__ fc1w,
                          const float* __restrict__ fc1b, const float* __restrict__ fc2w,
                          const float* __restrict__ fc2b, float* __restrict__ out,
                          float* __restrict__ sizef) {
  int r = blockIdx.x * 256 + threadIdx.x;
  float hr[16];
  LOAD16(hr, h + (size_t)r * DP);
  float s = fc2b[0];
  #pragma unroll
  for (int i = 0; i < 14; i++) {
    float t = fc1b[i];
    #pragma unroll
    for (int d = 0; d < 14; d++) t = fmaf(fc1w[i * 14 + d], hr[d], t);
    s = fmaf(t, fc2w[i], s);
  }
  out[r] = s;
  int si = (int)s;  // trunc toward zero, matches astype(int32)
  sizef[r] = (float)si;
}

// ---------------- regression head: fc3 -> fc4 -> fc5, masked ----------------
__global__ __launch_bounds__(256, 2) void head_reg(
    const float* __restrict__ x, const float* __restrict__ y,
    const float* __restrict__ sizef,
    const float* __restrict__ w3, const float* __restrict__ b3,
    const float* __restrict__ w4, const float* __restrict__ b4,
    const float* __restrict__ w5, const float* __restrict__ b5,
    float* __restrict__ outr) {
  __shared__ float RT[51][16];     // reg_in transposed [k][row]
  __shared__ float R1[16][HID];
  __shared__ float R2[16][HID];
  __shared__ float red[16][4];
  const int tid = threadIdx.x;
  const int rbase = blockIdx.x * 16;
  for (int idx = tid; idx < 51 * 16; idx += 256) {
    int rr = idx & 15, k = idx >> 4;
    float v;
    if (k == 0)       v = sizef[rbase + rr];
    else if (k < 15)  v = x[(size_t)(rbase + rr) * 14 + (k - 1)];
    else              v = y[(size_t)(rbase + rr) * 36 + (k - 15)];
    RT[k][rr] = v;
  }
  __syncthreads();
  const int j = tid;
  // fc3: 51 -> 256, relu
  float acc[16];
  float bj = b3[j];
  #pragma unroll
  for (int rr = 0; rr < 16; rr++) acc[rr] = bj;
  for (int k = 0; k < 51; k++) {
    float w = w3[(size_t)j * 51 + k];
    float t[16];
    LOAD16(t, &RT[k][0]);
    #pragma unroll
    for (int rr = 0; rr < 16; rr++) acc[rr] = fmaf(t[rr], w, acc[rr]);
  }
  #pragma unroll
  for (int rr = 0; rr < 16; rr++) R1[rr][j] = fmaxf(acc[rr], 0.f);
  __syncthreads();
  // fc4: 256 -> 256, relu
  float acc2[16];
  float b4j = b4[j];
  #pragma unroll
  for (int rr = 0; rr < 16; rr++) acc2[rr] = b4j;
  const float4* w44 = (const float4*)(w4 + (size_t)j * HID);
  for (int k4 = 0; k4 < HID / 4; k4++) {
    float4 w = w44[k4];
    #pragma unroll
    for (int rr = 0; rr < 16; rr++) {
      float4 t = ((const float4*)&R1[rr][0])[k4];
      acc2[rr] = fmaf(t.x, w.x, fmaf(t.y, w.y, fmaf(t.z, w.z, fmaf(t.w, w.w, acc2[rr]))));
    }
  }
  float w5j = w5[j];
  #pragma unroll
  for (int rr = 0; rr < 16; rr++) R2[rr][j] = fmaxf(acc2[rr], 0.f) * w5j;
  __syncthreads();
  // fc5 reduce: 64 lanes, each sums a quarter-row of 64
  if (tid < 64) {
    int rr = tid >> 2, seg = tid & 3;
    const float4* r2 = (const float4*)&R2[rr][seg * 64];
    float s0 = 0.f, s1 = 0.f, s2 = 0.f, s3 = 0.f;
    #pragma unroll
    for (int q = 0; q < 16; q += 4) {
      float4 a0 = r2[q], a1 = r2[q + 1], a2 = r2[q + 2], a3 = r2[q + 3];
      s0 += (a0.x + a0.y) + (a0.z + a0.w);
      s1 += (a1.x + a1.y) + (a1.z + a1.w);
      s2 += (a2.x + a2.y) + (a2.z + a2.w);
      s3 += (a3.x + a3.y) + (a3.z + a3.w);
    }
    red[rr][seg] = (s0 + s1) + (s2 + s3);
  }
  __syncthreads();
  if (tid < 16) {
    int rr = tid;
    float val = ((red[rr][0] + red[rr][1]) + (red[rr][2] + red[rr][3])) + b5[0];
    float sz = sizef[rbase + rr];
    outr[rbase + rr] = (sz != 0.f) ? val : 0.f;
  }
}

extern "C" void kernel_launch(void* const* d_in, const int* in_sizes, int n_in,
                              void* d_out, int out_size, void* d_ws, size_t ws_size,
                              hipStream_t stream) {
  const float* x    = (const float*)d_in[0];
  const float* y    = (const float*)d_in[1];
  const float* wqkv = (const float*)d_in[2];
  const float* bqkv = (const float*)d_in[3];
  const float* wo   = (const float*)d_in[4];
  const float* bo   = (const float*)d_in[5];
  const float* ln1g = (const float*)d_in[6];
  const float* ln1b = (const float*)d_in[7];
  const float* ffw1 = (const float*)d_in[8];
  const float* ffb1 = (const float*)d_in[9];
  const float* ffw2 = (const float*)d_in[10];
  const float* ffb2 = (const float*)d_in[11];
  const float* ln2g = (const float*)d_in[12];
  const float* ln2b = (const float*)d_in[13];
  const float* fc1w = (const float*)d_in[14];
  const float* fc1b = (const float*)d_in[15];
  const float* fc2w = (const float*)d_in[16];
  const float* fc2b = (const float*)d_in[17];
  const float* fc3w = (const float*)d_in[18];
  const float* fc3b = (const float*)d_in[19];
  const float* fc4w = (const float*)d_in[20];
  const float* fc4b = (const float*)d_in[21];
  const float* fc5w = (const float*)d_in[22];
  const float* fc5b = (const float*)d_in[23];

  float* ws = (float*)d_ws;
  float* h    = ws;                       // 8192*16
  float* Q    = ws + 131072;
  float* K    = ws + 262144;
  float* V    = ws + 393216;
  float* aacc = ws + 524288;              // 8192*16
  float* facc = ws + 655360;              // 8192*16
  float* sizef = ws + 786432;             // 8192

  float* out = (float*)d_out;

  copy_x<<<32, 256, 0, stream>>>(x, h);
  for (int l = 0; l < 2; l++) {
    qkv_proj<<<32, 256, 0, stream>>>(h, wqkv + (size_t)l * 42 * 14, bqkv + (size_t)l * 42,
                                     Q, K, V, aacc);
    attn_phase1<<<dim3(16, NCH), 256, 0, stream>>>(Q, K, V, aacc);
    attn_combine_ln1<<<32, 256, 0, stream>>>(h, aacc, wo + (size_t)l * 196,
                                             bo + (size_t)l * 14, ln1g + (size_t)l * 14,
                                             ln1b + (size_t)l * 14, facc);
    ffn_phase1<<<dim3(16, NFCH), 256, 0, stream>>>(h, ffw1 + (size_t)l * FF * 14,
                                                   ffb1 + (size_t)l * FF,
                                                   ffw2 + (size_t)l * 14 * FF, facc);
    ffn_combine_ln2<<<32, 256, 0, stream>>>(h, facc, ffb2 + (size_t)l * 14,
                                            ln2g + (size_t)l * 14, ln2b + (size_t)l * 14);
  }
  head_size<<<32, 256, 0, stream>>>(h, fc1w, fc1b, fc2w, fc2b, out, sizef);
  head_reg<<<512, 256, 0, stream>>>(x, y, sizef, fc3w, fc3b, fc4w, fc4b, fc5w, fc5b,
                                    out + NN);
}

// Round 3
// 425.999 us; speedup vs baseline: 4.7121x; 4.7121x over previous
//
#include <hip/hip_runtime.h>
#include <math.h>

#define NN 8192
#define DD 14
#define DP 16
#define FF 2048
#define HID 256
#define LN_EPS 1e-5f
#define NCH 32      // attention key chunks
#define CHK 256     // keys per chunk
#define FCH 64      // ffn j per chunk
#define NFCH 32     // ffn chunks
#define QSCALE (1.4426950408889634f / 3.7416573867739413f)  // log2(e)/sqrt(14)

#define LOAD16(dst, srcp) { \
  const float4* _p = (const float4*)(srcp); \
  float4 _a = _p[0], _b = _p[1], _c = _p[2], _d = _p[3]; \
  dst[0]=_a.x; dst[1]=_a.y; dst[2]=_a.z; dst[3]=_a.w; \
  dst[4]=_b.x; dst[5]=_b.y; dst[6]=_b.z; dst[7]=_b.w; \
  dst[8]=_c.x; dst[9]=_c.y; dst[10]=_c.z; dst[11]=_c.w; \
  dst[12]=_d.x; dst[13]=_d.y; dst[14]=_d.z; dst[15]=_d.w; }

#define STORE16(dstp, src) { \
  float4* _p = (float4*)(dstp); \
  _p[0] = make_float4(src[0], src[1], src[2], src[3]); \
  _p[1] = make_float4(src[4], src[5], src[6], src[7]); \
  _p[2] = make_float4(src[8], src[9], src[10], src[11]); \
  _p[3] = make_float4(src[12], src[13], src[14], src[15]); }

static __device__ __forceinline__ float fast_exp2(float x) {
#if __has_builtin(__builtin_amdgcn_exp2f)
  return __builtin_amdgcn_exp2f(x);
#else
  return exp2f(x);
#endif
}

// ---------------- copy x -> padded h ----------------
__global__ void copy_x(const float* __restrict__ x, float* __restrict__ h) {
  int r = blockIdx.x * 256 + threadIdx.x;
  float v[16];
  #pragma unroll
  for (int d = 0; d < 14; d++) v[d] = x[(size_t)r * 14 + d];
  v[14] = 0.f; v[15] = 0.f;
  STORE16(h + (size_t)r * DP, v);
}

// ---------------- qkv projection ----------------
__global__ void qkv_proj(const float* __restrict__ h, const float* __restrict__ wqkv,
                         const float* __restrict__ bqkv, float* __restrict__ Q,
                         float* __restrict__ K, float* __restrict__ V) {
  int r = blockIdx.x * 256 + threadIdx.x;
  float hr[16];
  LOAD16(hr, h + (size_t)r * DP);
  #pragma unroll 6
  for (int c = 0; c < 42; c++) {
    const float* w = wqkv + c * 14;
    float s = bqkv[c];
    #pragma unroll
    for (int d = 0; d < 14; d++) s = fmaf(hr[d], w[d], s);
    if (c < 14)       Q[(size_t)r * DP + c]        = s * QSCALE;
    else if (c < 28)  K[(size_t)r * DP + (c - 14)] = s;
    else              V[(size_t)r * DP + (c - 28)] = s;
  }
  Q[(size_t)r * DP + 14] = 0.f; Q[(size_t)r * DP + 15] = 0.f;
  K[(size_t)r * DP + 14] = 0.f; K[(size_t)r * DP + 15] = 0.f;
  V[(size_t)r * DP + 14] = 0.f; V[(size_t)r * DP + 15] = 0.f;
}

// ------- attention phase 1: no-max exp2, plain-sum partials, 1 row/thread -------
__global__ __launch_bounds__(256, 4) void attn_phase1(
    const float* __restrict__ Q, const float* __restrict__ Kb,
    const float* __restrict__ Vb, float* __restrict__ part) {
  __shared__ float Ks[CHK][DP];
  __shared__ float Vs[CHK][DP];
  const int tid = threadIdx.x;
  const int kBase = blockIdx.y * CHK;
  for (int idx = tid; idx < CHK * 4; idx += 256) {
    int j = idx >> 2, c = idx & 3;
    ((float4*)&Ks[j][0])[c] = ((const float4*)(Kb + (size_t)(kBase + j) * DP))[c];
    ((float4*)&Vs[j][0])[c] = ((const float4*)(Vb + (size_t)(kBase + j) * DP))[c];
  }
  __syncthreads();
  const int r = blockIdx.x * 256 + tid;
  float q[16];
  LOAD16(q, Q + (size_t)r * DP);
  float a[14];
  #pragma unroll
  for (int d = 0; d < 14; d++) a[d] = 0.f;
  float l = 0.f;

  #pragma unroll 2
  for (int j = 0; j < CHK; j++) {
    float kv[16];
    LOAD16(kv, &Ks[j][0]);
    float s0 = 0.f, s1 = 0.f, s2 = 0.f, s3 = 0.f;
    #pragma unroll
    for (int d = 0; d < 4; d++) {
      s0 = fmaf(q[d],      kv[d],      s0);
      s1 = fmaf(q[d + 4],  kv[d + 4],  s1);
      s2 = fmaf(q[d + 8],  kv[d + 8],  s2);
      s3 = fmaf(q[d + 12], kv[d + 12], s3);
    }
    float p = fast_exp2((s0 + s1) + (s2 + s3));
    float vv[16];
    LOAD16(vv, &Vs[j][0]);
    l += p;
    #pragma unroll
    for (int d = 0; d < 14; d++) a[d] = fmaf(p, vv[d], a[d]);
  }
  float o[16];
  o[0] = l;
  #pragma unroll
  for (int d = 0; d < 14; d++) o[1 + d] = a[d];
  o[15] = 0.f;
  // chunk-major: lanes write consecutive 64B lines
  STORE16(part + ((size_t)blockIdx.y * NN + r) * 16, o);
}

// ---- attention combine + out-proj + residual + LN1 ----
__global__ void attn_combine_ln1(float* __restrict__ h, const float* __restrict__ part,
                                 const float* __restrict__ wo, const float* __restrict__ bo,
                                 const float* __restrict__ g, const float* __restrict__ b) {
  int r = blockIdx.x * 256 + threadIdx.x;
  float L = 0.f;
  float A[14];
  #pragma unroll
  for (int d = 0; d < 14; d++) A[d] = 0.f;
  for (int c = 0; c < NCH; c++) {
    float p[16];
    LOAD16(p, part + ((size_t)c * NN + r) * 16);
    L += p[0];
    #pragma unroll
    for (int d = 0; d < 14; d++) A[d] += p[1 + d];
  }
  float inv = 1.f / L;
  float a[14];
  #pragma unroll
  for (int d = 0; d < 14; d++) a[d] = A[d] * inv;
  float hr[16];
  LOAD16(hr, h + (size_t)r * DP);
  float xx[14];
  #pragma unroll
  for (int i = 0; i < 14; i++) {
    float s = bo[i];
    #pragma unroll
    for (int d = 0; d < 14; d++) s = fmaf(wo[i * 14 + d], a[d], s);
    xx[i] = hr[i] + s;
  }
  float mu = 0.f;
  #pragma unroll
  for (int i = 0; i < 14; i++) mu += xx[i];
  mu *= (1.f / 14.f);
  float var = 0.f;
  #pragma unroll
  for (int i = 0; i < 14; i++) { float t = xx[i] - mu; var = fmaf(t, t, var); }
  var *= (1.f / 14.f);
  float rs = rsqrtf(var + LN_EPS);
  float o[16];
  #pragma unroll
  for (int i = 0; i < 14; i++) o[i] = fmaf((xx[i] - mu) * rs, g[i], b[i]);
  o[14] = 0.f; o[15] = 0.f;
  STORE16(h + (size_t)r * DP, o);
}

// ---------------- fused FFN phase 1 (partials over j-chunks, 1 row/thread) --------
__global__ __launch_bounds__(256, 4) void ffn_phase1(
    const float* __restrict__ h, const float* __restrict__ w1,
    const float* __restrict__ b1, const float* __restrict__ w2,
    float* __restrict__ part) {
  __shared__ float W1s[FCH][16];
  __shared__ float W2s[FCH][16];
  __shared__ float b1s[FCH];
  const int tid = threadIdx.x;
  const int jbase = blockIdx.y * FCH;
  for (int idx = tid; idx < FCH * 16; idx += 256) {
    int j = idx >> 4, d = idx & 15;
    W1s[j][d] = (d < 14) ? w1[(size_t)(jbase + j) * 14 + d] : 0.f;
    W2s[j][d] = (d < 14) ? w2[(size_t)d * FF + jbase + j] : 0.f;
  }
  if (tid < FCH) b1s[tid] = b1[jbase + tid];
  __syncthreads();
  const int r = blockIdx.x * 256 + tid;
  float hr[16];
  LOAD16(hr, h + (size_t)r * DP);
  float a[14];
  #pragma unroll
  for (int d = 0; d < 14; d++) a[d] = 0.f;
  #pragma unroll 2
  for (int j = 0; j < FCH; j++) {
    float w1v[16];
    LOAD16(w1v, &W1s[j][0]);
    float s0 = 0.f, s1 = 0.f, s2 = 0.f, s3 = 0.f;
    #pragma unroll
    for (int d = 0; d < 4; d++) {
      s0 = fmaf(hr[d],      w1v[d],      s0);
      s1 = fmaf(hr[d + 4],  w1v[d + 4],  s1);
      s2 = fmaf(hr[d + 8],  w1v[d + 8],  s2);
      s3 = fmaf(hr[d + 12], w1v[d + 12], s3);
    }
    float t = fmaxf(((s0 + s1) + (s2 + s3)) + b1s[j], 0.f);
    float w2v[16];
    LOAD16(w2v, &W2s[j][0]);
    #pragma unroll
    for (int d = 0; d < 14; d++) a[d] = fmaf(t, w2v[d], a[d]);
  }
  float o[16];
  #pragma unroll
  for (int d = 0; d < 14; d++) o[d] = a[d];
  o[14] = 0.f; o[15] = 0.f;
  STORE16(part + ((size_t)blockIdx.y * NN + r) * 16, o);
}

// ---------------- FFN combine + residual + LN2 ----------------
__global__ void ffn_combine_ln2(float* __restrict__ h, const float* __restrict__ part,
                                const float* __restrict__ b2, const float* __restrict__ g,
                                const float* __restrict__ b) {
  int r = blockIdx.x * 256 + threadIdx.x;
  float f[14];
  #pragma unroll
  for (int d = 0; d < 14; d++) f[d] = b2[d];
  for (int c = 0; c < NFCH; c++) {
    float p[16];
    LOAD16(p, part + ((size_t)c * NN + r) * 16);
    #pragma unroll
    for (int d = 0; d < 14; d++) f[d] += p[d];
  }
  float hr[16];
  LOAD16(hr, h + (size_t)r * DP);
  float xx[14];
  #pragma unroll
  for (int i = 0; i < 14; i++) xx[i] = hr[i] + f[i];
  float mu = 0.f;
  #pragma unroll
  for (int i = 0; i < 14; i++) mu += xx[i];
  mu *= (1.f / 14.f);
  float var = 0.f;
  #pragma unroll
  for (int i = 0; i < 14; i++) { float t = xx[i] - mu; var = fmaf(t, t, var); }
  var *= (1.f / 14.f);
  float rs = rsqrtf(var + LN_EPS);
  float o[16];
  #pragma unroll
  for (int i = 0; i < 14; i++) o[i] = fmaf((xx[i] - mu) * rs, g[i], b[i]);
  o[14] = 0.f; o[15] = 0.f;
  STORE16(h + (size_t)r * DP, o);
}

// ---------------- size head: fc1 -> fc2 -> size_out ----------------
__global__ void head_size(const float* __restrict__ h, const float* __restrict__ fc1w,
                          const float* __restrict__ fc1b, const float* __restrict__ fc2w,
                          const float* __restrict__ fc2b, float* __restrict__ out,
                          float* __restrict__ sizef) {
  int r = blockIdx.x * 256 + threadIdx.x;
  float hr[16];
  LOAD16(hr, h + (size_t)r * DP);
  float s = fc2b[0];
  #pragma unroll
  for (int i = 0; i < 14; i++) {
    float t = fc1b[i];
    #pragma unroll
    for (int d = 0; d < 14; d++) t = fmaf(fc1w[i * 14 + d], hr[d], t);
    s = fmaf(t, fc2w[i], s);
  }
  out[r] = s;
  int si = (int)s;  // trunc toward zero, matches astype(int32)
  sizef[r] = (float)si;
}

// ---------------- regression head: fc3 -> fc4 -> fc5, masked ----------------
__global__ __launch_bounds__(256, 2) void head_reg(
    const float* __restrict__ x, const float* __restrict__ y,
    const float* __restrict__ sizef,
    const float* __restrict__ w3, const float* __restrict__ b3,
    const float* __restrict__ w4, const float* __restrict__ b4,
    const float* __restrict__ w5, const float* __restrict__ b5,
    float* __restrict__ outr) {
  __shared__ float RT[51][16];     // reg_in transposed [k][row]
  __shared__ float R1[16][HID];
  __shared__ float R2[16][HID];
  __shared__ float red[16][4];
  const int tid = threadIdx.x;
  const int rbase = blockIdx.x * 16;
  for (int idx = tid; idx < 51 * 16; idx += 256) {
    int rr = idx & 15, k = idx >> 4;
    float v;
    if (k == 0)       v = sizef[rbase + rr];
    else if (k < 15)  v = x[(size_t)(rbase + rr) * 14 + (k - 1)];
    else              v = y[(size_t)(rbase + rr) * 36 + (k - 15)];
    RT[k][rr] = v;
  }
  __syncthreads();
  const int j = tid;
  // fc3: 51 -> 256, relu
  float acc[16];
  float bj = b3[j];
  #pragma unroll
  for (int rr = 0; rr < 16; rr++) acc[rr] = bj;
  for (int k = 0; k < 51; k++) {
    float w = w3[(size_t)j * 51 + k];
    float t[16];
    LOAD16(t, &RT[k][0]);
    #pragma unroll
    for (int rr = 0; rr < 16; rr++) acc[rr] = fmaf(t[rr], w, acc[rr]);
  }
  #pragma unroll
  for (int rr = 0; rr < 16; rr++) R1[rr][j] = fmaxf(acc[rr], 0.f);
  __syncthreads();
  // fc4: 256 -> 256, relu
  float acc2[16];
  float b4j = b4[j];
  #pragma unroll
  for (int rr = 0; rr < 16; rr++) acc2[rr] = b4j;
  const float4* w44 = (const float4*)(w4 + (size_t)j * HID);
  for (int k4 = 0; k4 < HID / 4; k4++) {
    float4 w = w44[k4];
    #pragma unroll
    for (int rr = 0; rr < 16; rr++) {
      float4 t = ((const float4*)&R1[rr][0])[k4];
      acc2[rr] = fmaf(t.x, w.x, fmaf(t.y, w.y, fmaf(t.z, w.z, fmaf(t.w, w.w, acc2[rr]))));
    }
  }
  float w5j = w5[j];
  #pragma unroll
  for (int rr = 0; rr < 16; rr++) R2[rr][j] = fmaxf(acc2[rr], 0.f) * w5j;
  __syncthreads();
  // fc5 reduce: 64 lanes, each sums a quarter-row of 64
  if (tid < 64) {
    int rr = tid >> 2, seg = tid & 3;
    const float4* r2 = (const float4*)&R2[rr][seg * 64];
    float s0 = 0.f, s1 = 0.f, s2 = 0.f, s3 = 0.f;
    #pragma unroll
    for (int q = 0; q < 16; q += 4) {
      float4 a0 = r2[q], a1 = r2[q + 1], a2 = r2[q + 2], a3 = r2[q + 3];
      s0 += (a0.x + a0.y) + (a0.z + a0.w);
      s1 += (a1.x + a1.y) + (a1.z + a1.w);
      s2 += (a2.x + a2.y) + (a2.z + a2.w);
      s3 += (a3.x + a3.y) + (a3.z + a3.w);
    }
    red[rr][seg] = (s0 + s1) + (s2 + s3);
  }
  __syncthreads();
  if (tid < 16) {
    int rr = tid;
    float val = ((red[rr][0] + red[rr][1]) + (red[rr][2] + red[rr][3])) + b5[0];
    float sz = sizef[rbase + rr];
    outr[rbase + rr] = (sz != 0.f) ? val : 0.f;
  }
}

extern "C" void kernel_launch(void* const* d_in, const int* in_sizes, int n_in,
                              void* d_out, int out_size, void* d_ws, size_t ws_size,
                              hipStream_t stream) {
  const float* x    = (const float*)d_in[0];
  const float* y    = (const float*)d_in[1];
  const float* wqkv = (const float*)d_in[2];
  const float* bqkv = (const float*)d_in[3];
  const float* wo   = (const float*)d_in[4];
  const float* bo   = (const float*)d_in[5];
  const float* ln1g = (const float*)d_in[6];
  const float* ln1b = (const float*)d_in[7];
  const float* ffw1 = (const float*)d_in[8];
  const float* ffb1 = (const float*)d_in[9];
  const float* ffw2 = (const float*)d_in[10];
  const float* ffb2 = (const float*)d_in[11];
  const float* ln2g = (const float*)d_in[12];
  const float* ln2b = (const float*)d_in[13];
  const float* fc1w = (const float*)d_in[14];
  const float* fc1b = (const float*)d_in[15];
  const float* fc2w = (const float*)d_in[16];
  const float* fc2b = (const float*)d_in[17];
  const float* fc3w = (const float*)d_in[18];
  const float* fc3b = (const float*)d_in[19];
  const float* fc4w = (const float*)d_in[20];
  const float* fc4b = (const float*)d_in[21];
  const float* fc5w = (const float*)d_in[22];
  const float* fc5b = (const float*)d_in[23];

  float* ws = (float*)d_ws;
  float* h    = ws;                       // 8192*16
  float* Q    = ws + 131072;
  float* K    = ws + 262144;
  float* V    = ws + 393216;
  float* part = ws + 524288;              // 8192*32*16 = 4194304
  float* sizef = ws + 524288 + 4194304;   // 8192

  float* out = (float*)d_out;

  copy_x<<<32, 256, 0, stream>>>(x, h);
  for (int l = 0; l < 2; l++) {
    qkv_proj<<<32, 256, 0, stream>>>(h, wqkv + (size_t)l * 42 * 14, bqkv + (size_t)l * 42,
                                     Q, K, V);
    attn_phase1<<<dim3(32, NCH), 256, 0, stream>>>(Q, K, V, part);
    attn_combine_ln1<<<32, 256, 0, stream>>>(h, part, wo + (size_t)l * 196,
                                             bo + (size_t)l * 14, ln1g + (size_t)l * 14,
                                             ln1b + (size_t)l * 14);
    ffn_phase1<<<dim3(32, NFCH), 256, 0, stream>>>(h, ffw1 + (size_t)l * FF * 14,
                                                   ffb1 + (size_t)l * FF,
                                                   ffw2 + (size_t)l * 14 * FF, part);
    ffn_combine_ln2<<<32, 256, 0, stream>>>(h, part, ffb2 + (size_t)l * 14,
                                            ln2g + (size_t)l * 14, ln2b + (size_t)l * 14);
  }
  head_size<<<32, 256, 0, stream>>>(h, fc1w, fc1b, fc2w, fc2b, out, sizef);
  head_reg<<<512, 256, 0, stream>>>(x, y, sizef, fc3w, fc3b, fc4w, fc4b, fc5w, fc5b,
                                    out + NN);
}

// Round 4
// 349.215 us; speedup vs baseline: 5.7482x; 1.2199x over previous
//
#include <hip/hip_runtime.h>
#include <math.h>

#define NN 8192
#define DD 14
#define DP 16
#define FF 2048
#define HID 256
#define LN_EPS 1e-5f
#define NCH 32      // attention key chunks (256 keys each)
#define FCH 64      // ffn j per chunk
#define NFCH 32     // ffn chunks
#define QSCALE (1.4426950408889634f / 3.7416573867739413f)  // log2(e)/sqrt(14)

typedef short bf16x8 __attribute__((ext_vector_type(8)));
typedef float f32x4 __attribute__((ext_vector_type(4)));

#define LOAD16(dst, srcp) { \
  const float4* _p = (const float4*)(srcp); \
  float4 _a = _p[0], _b = _p[1], _c = _p[2], _d = _p[3]; \
  dst[0]=_a.x; dst[1]=_a.y; dst[2]=_a.z; dst[3]=_a.w; \
  dst[4]=_b.x; dst[5]=_b.y; dst[6]=_b.z; dst[7]=_b.w; \
  dst[8]=_c.x; dst[9]=_c.y; dst[10]=_c.z; dst[11]=_c.w; \
  dst[12]=_d.x; dst[13]=_d.y; dst[14]=_d.z; dst[15]=_d.w; }

#define STORE16(dstp, src) { \
  float4* _p = (float4*)(dstp); \
  _p[0] = make_float4(src[0], src[1], src[2], src[3]); \
  _p[1] = make_float4(src[4], src[5], src[6], src[7]); \
  _p[2] = make_float4(src[8], src[9], src[10], src[11]); \
  _p[3] = make_float4(src[12], src[13], src[14], src[15]); }

static __device__ __forceinline__ float fast_exp2(float x) {
#if __has_builtin(__builtin_amdgcn_exp2f)
  return __builtin_amdgcn_exp2f(x);
#else
  return exp2f(x);
#endif
}

static __device__ __forceinline__ unsigned short bf_hi(float x) {
  return (unsigned short)(__float_as_uint(x) >> 16);
}
static __device__ __forceinline__ float bf_hi_f(float x) {
  return __uint_as_float(__float_as_uint(x) & 0xffff0000u);
}

// ---------------- copy x -> padded h ----------------
__global__ void copy_x(const float* __restrict__ x, float* __restrict__ h) {
  int r = blockIdx.x * 256 + threadIdx.x;
  float v[16];
  #pragma unroll
  for (int d = 0; d < 14; d++) v[d] = x[(size_t)r * 14 + d];
  v[14] = 0.f; v[15] = 0.f;
  STORE16(h + (size_t)r * DP, v);
}

// ------- qkv projection + split-bf16 packing for MFMA attention -------
// Qpack row (32 bf16 = 16 uints): [qhi(14),0,0 | qlo(14),0,0]
// KB1  row: [khi(14),0,0 | khi(14),0,0] ; KB2 row: [klo(14),0,0 | klo(14),0,0]
// VhiT[col][key] (16x8192 bf16): col<14 = vhi, col14 = 1.0, col15 = 0
// VloT[col][key]:                 col<14 = vlo, col14 = 0,   col15 = 0
__global__ void qkv_pack(const float* __restrict__ h, const float* __restrict__ wqkv,
                         const float* __restrict__ bqkv,
                         unsigned int* __restrict__ Qpack,
                         unsigned int* __restrict__ KB1, unsigned int* __restrict__ KB2,
                         unsigned short* __restrict__ VhiT,
                         unsigned short* __restrict__ VloT) {
  int r = blockIdx.x * 256 + threadIdx.x;
  float hr[16];
  LOAD16(hr, h + (size_t)r * DP);
  float q[14], k[14], v[14];
  #pragma unroll 6
  for (int c = 0; c < 42; c++) {
    const float* w = wqkv + c * 14;
    float s = bqkv[c];
    #pragma unroll
    for (int d = 0; d < 14; d++) s = fmaf(hr[d], w[d], s);
    if (c < 14)       q[c] = s * QSCALE;
    else if (c < 28)  k[c - 14] = s;
    else              v[c - 28] = s;
  }
  unsigned int qp[16], k1[16], k2[16];
  unsigned short qh[14], ql[14], kh[14], kl[14];
  #pragma unroll
  for (int d = 0; d < 14; d++) {
    qh[d] = bf_hi(q[d]);
    ql[d] = bf_hi(q[d] - bf_hi_f(q[d]));
    kh[d] = bf_hi(k[d]);
    kl[d] = bf_hi(k[d] - bf_hi_f(k[d]));
  }
  #pragma unroll
  for (int i = 0; i < 7; i++) {
    qp[i]     = (unsigned int)qh[2*i] | ((unsigned int)qh[2*i+1] << 16);
    qp[8 + i] = (unsigned int)ql[2*i] | ((unsigned int)ql[2*i+1] << 16);
    k1[i]     = (unsigned int)kh[2*i] | ((unsigned int)kh[2*i+1] << 16);
    k1[8 + i] = k1[i];
    k2[i]     = (unsigned int)kl[2*i] | ((unsigned int)kl[2*i+1] << 16);
    k2[8 + i] = k2[i];
  }
  qp[7] = 0; qp[15] = 0; k1[7] = 0; k1[15] = 0; k2[7] = 0; k2[15] = 0;
  uint4* Qp4 = (uint4*)(Qpack + (size_t)r * 16);
  uint4* K14 = (uint4*)(KB1 + (size_t)r * 16);
  uint4* K24 = (uint4*)(KB2 + (size_t)r * 16);
  #pragma unroll
  for (int i = 0; i < 4; i++) {
    Qp4[i] = make_uint4(qp[4*i], qp[4*i+1], qp[4*i+2], qp[4*i+3]);
    K14[i] = make_uint4(k1[4*i], k1[4*i+1], k1[4*i+2], k1[4*i+3]);
    K24[i] = make_uint4(k2[4*i], k2[4*i+1], k2[4*i+2], k2[4*i+3]);
  }
  #pragma unroll
  for (int d = 0; d < 14; d++) {
    VhiT[(size_t)d * NN + r] = bf_hi(v[d]);
    VloT[(size_t)d * NN + r] = bf_hi(v[d] - bf_hi_f(v[d]));
  }
  VhiT[(size_t)14 * NN + r] = 0x3F80;  // bf16 1.0 -> ones column = softmax denom
  VhiT[(size_t)15 * NN + r] = 0;
  VloT[(size_t)14 * NN + r] = 0;
  VloT[(size_t)15 * NN + r] = 0;
}

// ------- MFMA attention phase 1: per (128-row block, 256-key chunk) partials ------
// Each wave handles 32 q-rows; 8 inner iters of 32 keys.
// Partial layout: part[chunk][row][16]: cols 0..13 = sum(p*v), col14 = sum(p).
__global__ __launch_bounds__(256, 4) void attn_mfma(
    const unsigned int* __restrict__ Qpack, const unsigned int* __restrict__ KB1,
    const unsigned int* __restrict__ KB2, const unsigned short* __restrict__ VhiT,
    const unsigned short* __restrict__ VloT, float* __restrict__ part) {
  __shared__ float Plds[4][16][36];
  const int tid = threadIdx.x;
  const int wave = tid >> 6;
  const int lane = tid & 63;
  const int lo4 = lane & 15;
  const int hi4 = lane >> 4;
  const int qbase = blockIdx.x * 128 + wave * 32;
  const int kbase0 = blockIdx.y * 256;

  const bf16x8* Qp = (const bf16x8*)Qpack;   // row = 4 chunks of 8 bf16
  const bf16x8* B1 = (const bf16x8*)KB1;
  const bf16x8* B2 = (const bf16x8*)KB2;
  const bf16x8* Vh = (const bf16x8*)VhiT;    // [col][key] : col*1024 + key/8
  const bf16x8* Vl = (const bf16x8*)VloT;

  bf16x8 aQ0 = Qp[(size_t)(qbase + lo4) * 4 + hi4];
  bf16x8 aQ1 = Qp[(size_t)(qbase + 16 + lo4) * 4 + hi4];
  f32x4 acc0 = {0.f, 0.f, 0.f, 0.f};
  f32x4 acc1 = {0.f, 0.f, 0.f, 0.f};
  const f32x4 zero = {0.f, 0.f, 0.f, 0.f};

  for (int c = 0; c < 8; c++) {
    const int kb = kbase0 + c * 32;
    bf16x8 b1g0 = B1[(size_t)(kb + lo4) * 4 + hi4];
    bf16x8 b2g0 = B2[(size_t)(kb + lo4) * 4 + hi4];
    bf16x8 b1g1 = B1[(size_t)(kb + 16 + lo4) * 4 + hi4];
    bf16x8 b2g1 = B2[(size_t)(kb + 16 + lo4) * 4 + hi4];
    bf16x8 vh = Vh[(size_t)lo4 * 1024 + (kb >> 3) + hi4];
    bf16x8 vl = Vl[(size_t)lo4 * 1024 + (kb >> 3) + hi4];

    #pragma unroll
    for (int sub = 0; sub < 2; sub++) {
      bf16x8 aQ = sub ? aQ1 : aQ0;
      // S = Q.K^T (exact via hi+lo passes), fp32 accum
      f32x4 s0 = __builtin_amdgcn_mfma_f32_16x16x32_bf16(aQ, b1g0, zero, 0, 0, 0);
      s0 = __builtin_amdgcn_mfma_f32_16x16x32_bf16(aQ, b2g0, s0, 0, 0, 0);
      f32x4 s1 = __builtin_amdgcn_mfma_f32_16x16x32_bf16(aQ, b1g1, zero, 0, 0, 0);
      s1 = __builtin_amdgcn_mfma_f32_16x16x32_bf16(aQ, b2g1, s1, 0, 0, 0);
      // p = exp2(s); write C-layout -> LDS
      #pragma unroll
      for (int reg = 0; reg < 4; reg++) {
        Plds[wave][hi4 * 4 + reg][lo4]      = fast_exp2(s0[reg]);
        Plds[wave][hi4 * 4 + reg][16 + lo4] = fast_exp2(s1[reg]);
      }
      __asm__ volatile("s_waitcnt lgkmcnt(0)" ::: "memory");
      // read A-layout: row lo4, keys hi4*8..+7
      const float4* pr = (const float4*)&Plds[wave][lo4][hi4 * 8];
      float4 f0 = pr[0];
      float4 f1 = pr[1];
      float pv[8] = {f0.x, f0.y, f0.z, f0.w, f1.x, f1.y, f1.z, f1.w};
      bf16x8 ph, pl;
      #pragma unroll
      for (int i = 0; i < 8; i++) {
        unsigned int u = __float_as_uint(pv[i]);
        ph[i] = (short)(u >> 16);
        float rr = pv[i] - __uint_as_float(u & 0xffff0000u);
        pl[i] = (short)(__float_as_uint(rr) >> 16);
      }
      f32x4 acc = sub ? acc1 : acc0;
      acc = __builtin_amdgcn_mfma_f32_16x16x32_bf16(ph, vh, acc, 0, 0, 0);
      acc = __builtin_amdgcn_mfma_f32_16x16x32_bf16(pl, vh, acc, 0, 0, 0);
      acc = __builtin_amdgcn_mfma_f32_16x16x32_bf16(ph, vl, acc, 0, 0, 0);
      if (sub) acc1 = acc; else acc0 = acc;
      __asm__ volatile("s_waitcnt lgkmcnt(0)" ::: "memory");
    }
  }
  // store partials: lane holds O[row=hi4*4+reg][col=lo4]
  float* pbase = part + (size_t)blockIdx.y * NN * 16;
  #pragma unroll
  for (int reg = 0; reg < 4; reg++) {
    int row0 = qbase + hi4 * 4 + reg;
    pbase[(size_t)row0 * 16 + lo4] = acc0[reg];
    pbase[(size_t)(row0 + 16) * 16 + lo4] = acc1[reg];
  }
}

// ---- attention combine + out-proj + residual + LN1 (l at col 14) ----
__global__ void attn_combine_ln1(float* __restrict__ h, const float* __restrict__ part,
                                 const float* __restrict__ wo, const float* __restrict__ bo,
                                 const float* __restrict__ g, const float* __restrict__ b) {
  int r = blockIdx.x * 256 + threadIdx.x;
  float L = 0.f;
  float A[14];
  #pragma unroll
  for (int d = 0; d < 14; d++) A[d] = 0.f;
  for (int c = 0; c < NCH; c++) {
    float p[16];
    LOAD16(p, part + ((size_t)c * NN + r) * 16);
    L += p[14];
    #pragma unroll
    for (int d = 0; d < 14; d++) A[d] += p[d];
  }
  float inv = 1.f / L;
  float a[14];
  #pragma unroll
  for (int d = 0; d < 14; d++) a[d] = A[d] * inv;
  float hr[16];
  LOAD16(hr, h + (size_t)r * DP);
  float xx[14];
  #pragma unroll
  for (int i = 0; i < 14; i++) {
    float s = bo[i];
    #pragma unroll
    for (int d = 0; d < 14; d++) s = fmaf(wo[i * 14 + d], a[d], s);
    xx[i] = hr[i] + s;
  }
  float mu = 0.f;
  #pragma unroll
  for (int i = 0; i < 14; i++) mu += xx[i];
  mu *= (1.f / 14.f);
  float var = 0.f;
  #pragma unroll
  for (int i = 0; i < 14; i++) { float t = xx[i] - mu; var = fmaf(t, t, var); }
  var *= (1.f / 14.f);
  float rs = rsqrtf(var + LN_EPS);
  float o[16];
  #pragma unroll
  for (int i = 0; i < 14; i++) o[i] = fmaf((xx[i] - mu) * rs, g[i], b[i]);
  o[14] = 0.f; o[15] = 0.f;
  STORE16(h + (size_t)r * DP, o);
}

// ---------------- fused FFN phase 1 (partials over j-chunks, 1 row/thread) --------
__global__ __launch_bounds__(256, 4) void ffn_phase1(
    const float* __restrict__ h, const float* __restrict__ w1,
    const float* __restrict__ b1, const float* __restrict__ w2,
    float* __restrict__ part) {
  __shared__ float W1s[FCH][16];
  __shared__ float W2s[FCH][16];
  __shared__ float b1s[FCH];
  const int tid = threadIdx.x;
  const int jbase = blockIdx.y * FCH;
  for (int idx = tid; idx < FCH * 16; idx += 256) {
    int j = idx >> 4, d = idx & 15;
    W1s[j][d] = (d < 14) ? w1[(size_t)(jbase + j) * 14 + d] : 0.f;
    W2s[j][d] = (d < 14) ? w2[(size_t)d * FF + jbase + j] : 0.f;
  }
  if (tid < FCH) b1s[tid] = b1[jbase + tid];
  __syncthreads();
  const int r = blockIdx.x * 256 + tid;
  float hr[16];
  LOAD16(hr, h + (size_t)r * DP);
  float a[14];
  #pragma unroll
  for (int d = 0; d < 14; d++) a[d] = 0.f;
  #pragma unroll 2
  for (int j = 0; j < FCH; j++) {
    float w1v[16];
    LOAD16(w1v, &W1s[j][0]);
    float s0 = 0.f, s1 = 0.f, s2 = 0.f, s3 = 0.f;
    #pragma unroll
    for (int d = 0; d < 4; d++) {
      s0 = fmaf(hr[d],      w1v[d],      s0);
      s1 = fmaf(hr[d + 4],  w1v[d + 4],  s1);
      s2 = fmaf(hr[d + 8],  w1v[d + 8],  s2);
      s3 = fmaf(hr[d + 12], w1v[d + 12], s3);
    }
    float t = fmaxf(((s0 + s1) + (s2 + s3)) + b1s[j], 0.f);
    float w2v[16];
    LOAD16(w2v, &W2s[j][0]);
    #pragma unroll
    for (int d = 0; d < 14; d++) a[d] = fmaf(t, w2v[d], a[d]);
  }
  float o[16];
  #pragma unroll
  for (int d = 0; d < 14; d++) o[d] = a[d];
  o[14] = 0.f; o[15] = 0.f;
  STORE16(part + ((size_t)blockIdx.y * NN + r) * 16, o);
}

// ---------------- FFN combine + residual + LN2 ----------------
__global__ void ffn_combine_ln2(float* __restrict__ h, const float* __restrict__ part,
                                const float* __restrict__ b2, const float* __restrict__ g,
                                const float* __restrict__ b) {
  int r = blockIdx.x * 256 + threadIdx.x;
  float f[14];
  #pragma unroll
  for (int d = 0; d < 14; d++) f[d] = b2[d];
  for (int c = 0; c < NFCH; c++) {
    float p[16];
    LOAD16(p, part + ((size_t)c * NN + r) * 16);
    #pragma unroll
    for (int d = 0; d < 14; d++) f[d] += p[d];
  }
  float hr[16];
  LOAD16(hr, h + (size_t)r * DP);
  float xx[14];
  #pragma unroll
  for (int i = 0; i < 14; i++) xx[i] = hr[i] + f[i];
  float mu = 0.f;
  #pragma unroll
  for (int i = 0; i < 14; i++) mu += xx[i];
  mu *= (1.f / 14.f);
  float var = 0.f;
  #pragma unroll
  for (int i = 0; i < 14; i++) { float t = xx[i] - mu; var = fmaf(t, t, var); }
  var *= (1.f / 14.f);
  float rs = rsqrtf(var + LN_EPS);
  float o[16];
  #pragma unroll
  for (int i = 0; i < 14; i++) o[i] = fmaf((xx[i] - mu) * rs, g[i], b[i]);
  o[14] = 0.f; o[15] = 0.f;
  STORE16(h + (size_t)r * DP, o);
}

// ---------------- size head: fc1 -> fc2 -> size_out ----------------
__global__ void head_size(const float* __restrict__ h, const float* __restrict__ fc1w,
                          const float* __restrict__ fc1b, const float* __restrict__ fc2w,
                          const float* __restrict__ fc2b, float* __restrict__ out,
                          float* __restrict__ sizef) {
  int r = blockIdx.x * 256 + threadIdx.x;
  float hr[16];
  LOAD16(hr, h + (size_t)r * DP);
  float s = fc2b[0];
  #pragma unroll
  for (int i = 0; i < 14; i++) {
    float t = fc1b[i];
    #pragma unroll
    for (int d = 0; d < 14; d++) t = fmaf(fc1w[i * 14 + d], hr[d], t);
    s = fmaf(t, fc2w[i], s);
  }
  out[r] = s;
  int si = (int)s;  // trunc toward zero, matches astype(int32)
  sizef[r] = (float)si;
}

// ---------------- regression head: fc3 -> fc4 -> fc5, masked ----------------
__global__ __launch_bounds__(256, 2) void head_reg(
    const float* __restrict__ x, const float* __restrict__ y,
    const float* __restrict__ sizef,
    const float* __restrict__ w3, const float* __restrict__ b3,
    const float* __restrict__ w4, const float* __restrict__ b4,
    const float* __restrict__ w5, const float* __restrict__ b5,
    float* __restrict__ outr) {
  __shared__ float RT[51][16];     // reg_in transposed [k][row]
  __shared__ float R1[16][HID];
  __shared__ float R2[16][HID];
  __shared__ float red[16][4];
  const int tid = threadIdx.x;
  const int rbase = blockIdx.x * 16;
  for (int idx = tid; idx < 51 * 16; idx += 256) {
    int rr = idx & 15, k = idx >> 4;
    float v;
    if (k == 0)       v = sizef[rbase + rr];
    else if (k < 15)  v = x[(size_t)(rbase + rr) * 14 + (k - 1)];
    else              v = y[(size_t)(rbase + rr) * 36 + (k - 15)];
    RT[k][rr] = v;
  }
  __syncthreads();
  const int j = tid;
  // fc3: 51 -> 256, relu
  float acc[16];
  float bj = b3[j];
  #pragma unroll
  for (int rr = 0; rr < 16; rr++) acc[rr] = bj;
  for (int k = 0; k < 51; k++) {
    float w = w3[(size_t)j * 51 + k];
    float t[16];
    LOAD16(t, &RT[k][0]);
    #pragma unroll
    for (int rr = 0; rr < 16; rr++) acc[rr] = fmaf(t[rr], w, acc[rr]);
  }
  #pragma unroll
  for (int rr = 0; rr < 16; rr++) R1[rr][j] = fmaxf(acc[rr], 0.f);
  __syncthreads();
  // fc4: 256 -> 256, relu
  float acc2[16];
  float b4j = b4[j];
  #pragma unroll
  for (int rr = 0; rr < 16; rr++) acc2[rr] = b4j;
  const float4* w44 = (const float4*)(w4 + (size_t)j * HID);
  for (int k4 = 0; k4 < HID / 4; k4++) {
    float4 w = w44[k4];
    #pragma unroll
    for (int rr = 0; rr < 16; rr++) {
      float4 t = ((const float4*)&R1[rr][0])[k4];
      acc2[rr] = fmaf(t.x, w.x, fmaf(t.y, w.y, fmaf(t.z, w.z, fmaf(t.w, w.w, acc2[rr]))));
    }
  }
  float w5j = w5[j];
  #pragma unroll
  for (int rr = 0; rr < 16; rr++) R2[rr][j] = fmaxf(acc2[rr], 0.f) * w5j;
  __syncthreads();
  // fc5 reduce: 64 lanes, each sums a quarter-row of 64
  if (tid < 64) {
    int rr = tid >> 2, seg = tid & 3;
    const float4* r2 = (const float4*)&R2[rr][seg * 64];
    float s0 = 0.f, s1 = 0.f, s2 = 0.f, s3 = 0.f;
    #pragma unroll
    for (int q = 0; q < 16; q += 4) {
      float4 a0 = r2[q], a1 = r2[q + 1], a2 = r2[q + 2], a3 = r2[q + 3];
      s0 += (a0.x + a0.y) + (a0.z + a0.w);
      s1 += (a1.x + a1.y) + (a1.z + a1.w);
      s2 += (a2.x + a2.y) + (a2.z + a2.w);
      s3 += (a3.x + a3.y) + (a3.z + a3.w);
    }
    red[rr][seg] = (s0 + s1) + (s2 + s3);
  }
  __syncthreads();
  if (tid < 16) {
    int rr = tid;
    float val = ((red[rr][0] + red[rr][1]) + (red[rr][2] + red[rr][3])) + b5[0];
    float sz = sizef[rbase + rr];
    outr[rbase + rr] = (sz != 0.f) ? val : 0.f;
  }
}

extern "C" void kernel_launch(void* const* d_in, const int* in_sizes, int n_in,
                              void* d_out, int out_size, void* d_ws, size_t ws_size,
                              hipStream_t stream) {
  const float* x    = (const float*)d_in[0];
  const float* y    = (const float*)d_in[1];
  const float* wqkv = (const float*)d_in[2];
  const float* bqkv = (const float*)d_in[3];
  const float* wo   = (const float*)d_in[4];
  const float* bo   = (const float*)d_in[5];
  const float* ln1g = (const float*)d_in[6];
  const float* ln1b = (const float*)d_in[7];
  const float* ffw1 = (const float*)d_in[8];
  const float* ffb1 = (const float*)d_in[9];
  const float* ffw2 = (const float*)d_in[10];
  const float* ffb2 = (const float*)d_in[11];
  const float* ln2g = (const float*)d_in[12];
  const float* ln2b = (const float*)d_in[13];
  const float* fc1w = (const float*)d_in[14];
  const float* fc1b = (const float*)d_in[15];
  const float* fc2w = (const float*)d_in[16];
  const float* fc2b = (const float*)d_in[17];
  const float* fc3w = (const float*)d_in[18];
  const float* fc3b = (const float*)d_in[19];
  const float* fc4w = (const float*)d_in[20];
  const float* fc4b = (const float*)d_in[21];
  const float* fc5w = (const float*)d_in[22];
  const float* fc5b = (const float*)d_in[23];

  float* ws = (float*)d_ws;
  float* h     = ws;                        // 131072 floats
  unsigned int*   Qpack = (unsigned int*)(ws + 131072);    // 8192*16 uints
  unsigned int*   KB1   = (unsigned int*)(ws + 262144);
  unsigned int*   KB2   = (unsigned int*)(ws + 393216);
  unsigned short* VhiT  = (unsigned short*)(ws + 524288);  // 16*8192 ushorts = 65536 f
  unsigned short* VloT  = (unsigned short*)(ws + 589824);
  float* part  = ws + 655360;               // 32*8192*16 = 4194304 floats
  float* sizef = ws + 655360 + 4194304;     // 8192

  float* out = (float*)d_out;

  copy_x<<<32, 256, 0, stream>>>(x, h);
  for (int l = 0; l < 2; l++) {
    qkv_pack<<<32, 256, 0, stream>>>(h, wqkv + (size_t)l * 42 * 14, bqkv + (size_t)l * 42,
                                     Qpack, KB1, KB2, VhiT, VloT);
    attn_mfma<<<dim3(64, NCH), 256, 0, stream>>>(Qpack, KB1, KB2, VhiT, VloT, part);
    attn_combine_ln1<<<32, 256, 0, stream>>>(h, part, wo + (size_t)l * 196,
                                             bo + (size_t)l * 14, ln1g + (size_t)l * 14,
                                             ln1b + (size_t)l * 14);
    ffn_phase1<<<dim3(32, NFCH), 256, 0, stream>>>(h, ffw1 + (size_t)l * FF * 14,
                                                   ffb1 + (size_t)l * FF,
                                                   ffw2 + (size_t)l * 14 * FF, part);
    ffn_combine_ln2<<<32, 256, 0, stream>>>(h, part, ffb2 + (size_t)l * 14,
                                            ln2g + (size_t)l * 14, ln2b + (size_t)l * 14);
  }
  head_size<<<32, 256, 0, stream>>>(h, fc1w, fc1b, fc2w, fc2b, out, sizef);
  head_reg<<<512, 256, 0, stream>>>(x, y, sizef, fc3w, fc3b, fc4w, fc4b, fc5w, fc5b,
                                    out + NN);
}

// Round 5
// 328.735 us; speedup vs baseline: 6.1063x; 1.0623x over previous
//
#include <hip/hip_runtime.h>
#include <math.h>

#define NN 8192
#define DD 14
#define DP 16
#define FF 2048
#define HID 256
#define LN_EPS 1e-5f
#define NCH 32      // attention key chunks (256 keys each)
#define FCH 64      // ffn j per chunk
#define NFCH 32     // ffn chunks
#define QSCALE (1.4426950408889634f / 3.7416573867739413f)  // log2(e)/sqrt(14)

typedef short bf16x8 __attribute__((ext_vector_type(8)));
typedef float f32x4 __attribute__((ext_vector_type(4)));

#define LOAD16(dst, srcp) { \
  const float4* _p = (const float4*)(srcp); \
  float4 _a = _p[0], _b = _p[1], _c = _p[2], _d = _p[3]; \
  dst[0]=_a.x; dst[1]=_a.y; dst[2]=_a.z; dst[3]=_a.w; \
  dst[4]=_b.x; dst[5]=_b.y; dst[6]=_b.z; dst[7]=_b.w; \
  dst[8]=_c.x; dst[9]=_c.y; dst[10]=_c.z; dst[11]=_c.w; \
  dst[12]=_d.x; dst[13]=_d.y; dst[14]=_d.z; dst[15]=_d.w; }

#define STORE16(dstp, src) { \
  float4* _p = (float4*)(dstp); \
  _p[0] = make_float4(src[0], src[1], src[2], src[3]); \
  _p[1] = make_float4(src[4], src[5], src[6], src[7]); \
  _p[2] = make_float4(src[8], src[9], src[10], src[11]); \
  _p[3] = make_float4(src[12], src[13], src[14], src[15]); }

static __device__ __forceinline__ float fast_exp2(float x) {
#if __has_builtin(__builtin_amdgcn_exp2f)
  return __builtin_amdgcn_exp2f(x);
#else
  return exp2f(x);
#endif
}

static __device__ __forceinline__ unsigned short bf_hi(float x) {
  return (unsigned short)(__float_as_uint(x) >> 16);
}
static __device__ __forceinline__ float bf_hi_f(float x) {
  return __uint_as_float(__float_as_uint(x) & 0xffff0000u);
}

// ---------------- copy x -> padded h ----------------
__global__ void copy_x(const float* __restrict__ x, float* __restrict__ h) {
  int r = blockIdx.x * 256 + threadIdx.x;
  float v[16];
  #pragma unroll
  for (int d = 0; d < 14; d++) v[d] = x[(size_t)r * 14 + d];
  v[14] = 0.f; v[15] = 0.f;
  STORE16(h + (size_t)r * DP, v);
}

// ------- pack w3/w4 into MFMA B-fragment layout (bf16 hi/lo) -------
// B frag for 16x16x32: lane holds B[k = ks*32 + (lane>>4)*8 + j][n = nt*16 + (lane&15)]
// B4 index fi = (nt*8 + ks)*64 + lane  (nt 0..15, ks 0..7)
// B3 index fi = (nt*2 + ks)*64 + lane  (nt 0..15, ks 0..1), k >= 51 zero-padded
__global__ void pack_head(const float* __restrict__ w3, const float* __restrict__ w4,
                          unsigned short* __restrict__ B3h, unsigned short* __restrict__ B3l,
                          unsigned short* __restrict__ B4h, unsigned short* __restrict__ B4l) {
  int t = blockIdx.x * 256 + threadIdx.x;   // 0..8191
  int lane = t & 63, ks = (t >> 6) & 7, nt = t >> 9;
  int n = nt * 16 + (lane & 15);
  int k0 = ks * 32 + (lane >> 4) * 8;
  unsigned int h4[4], l4[4];
  #pragma unroll
  for (int jj = 0; jj < 4; jj++) {
    unsigned short h2[2], l2[2];
    #pragma unroll
    for (int e = 0; e < 2; e++) {
      float v = w4[(size_t)n * 256 + k0 + jj * 2 + e];
      h2[e] = bf_hi(v);
      l2[e] = bf_hi(v - bf_hi_f(v));
    }
    h4[jj] = (unsigned int)h2[0] | ((unsigned int)h2[1] << 16);
    l4[jj] = (unsigned int)l2[0] | ((unsigned int)l2[1] << 16);
  }
  ((uint4*)B4h)[t] = make_uint4(h4[0], h4[1], h4[2], h4[3]);
  ((uint4*)B4l)[t] = make_uint4(l4[0], l4[1], l4[2], l4[3]);
  if (ks < 2) {
    int fi = (nt * 2 + ks) * 64 + lane;
    #pragma unroll
    for (int jj = 0; jj < 4; jj++) {
      unsigned short h2[2], l2[2];
      #pragma unroll
      for (int e = 0; e < 2; e++) {
        int k = k0 + jj * 2 + e;
        float v = (k < 51) ? w3[(size_t)n * 51 + k] : 0.f;
        h2[e] = bf_hi(v);
        l2[e] = bf_hi(v - bf_hi_f(v));
      }
      h4[jj] = (unsigned int)h2[0] | ((unsigned int)h2[1] << 16);
      l4[jj] = (unsigned int)l2[0] | ((unsigned int)l2[1] << 16);
    }
    ((uint4*)B3h)[fi] = make_uint4(h4[0], h4[1], h4[2], h4[3]);
    ((uint4*)B3l)[fi] = make_uint4(l4[0], l4[1], l4[2], l4[3]);
  }
}

// ------- qkv projection + split-bf16 packing for MFMA attention -------
__global__ void qkv_pack(const float* __restrict__ h, const float* __restrict__ wqkv,
                         const float* __restrict__ bqkv,
                         unsigned int* __restrict__ Qpack,
                         unsigned int* __restrict__ KB1, unsigned int* __restrict__ KB2,
                         unsigned short* __restrict__ VhiT,
                         unsigned short* __restrict__ VloT) {
  int r = blockIdx.x * 256 + threadIdx.x;
  float hr[16];
  LOAD16(hr, h + (size_t)r * DP);
  float q[14], k[14], v[14];
  #pragma unroll 6
  for (int c = 0; c < 42; c++) {
    const float* w = wqkv + c * 14;
    float s = bqkv[c];
    #pragma unroll
    for (int d = 0; d < 14; d++) s = fmaf(hr[d], w[d], s);
    if (c < 14)       q[c] = s * QSCALE;
    else if (c < 28)  k[c - 14] = s;
    else              v[c - 28] = s;
  }
  unsigned int qp[16], k1[16], k2[16];
  unsigned short qh[14], ql[14], kh[14], kl[14];
  #pragma unroll
  for (int d = 0; d < 14; d++) {
    qh[d] = bf_hi(q[d]);
    ql[d] = bf_hi(q[d] - bf_hi_f(q[d]));
    kh[d] = bf_hi(k[d]);
    kl[d] = bf_hi(k[d] - bf_hi_f(k[d]));
  }
  #pragma unroll
  for (int i = 0; i < 7; i++) {
    qp[i]     = (unsigned int)qh[2*i] | ((unsigned int)qh[2*i+1] << 16);
    qp[8 + i] = (unsigned int)ql[2*i] | ((unsigned int)ql[2*i+1] << 16);
    k1[i]     = (unsigned int)kh[2*i] | ((unsigned int)kh[2*i+1] << 16);
    k1[8 + i] = k1[i];
    k2[i]     = (unsigned int)kl[2*i] | ((unsigned int)kl[2*i+1] << 16);
    k2[8 + i] = k2[i];
  }
  qp[7] = 0; qp[15] = 0; k1[7] = 0; k1[15] = 0; k2[7] = 0; k2[15] = 0;
  uint4* Qp4 = (uint4*)(Qpack + (size_t)r * 16);
  uint4* K14 = (uint4*)(KB1 + (size_t)r * 16);
  uint4* K24 = (uint4*)(KB2 + (size_t)r * 16);
  #pragma unroll
  for (int i = 0; i < 4; i++) {
    Qp4[i] = make_uint4(qp[4*i], qp[4*i+1], qp[4*i+2], qp[4*i+3]);
    K14[i] = make_uint4(k1[4*i], k1[4*i+1], k1[4*i+2], k1[4*i+3]);
    K24[i] = make_uint4(k2[4*i], k2[4*i+1], k2[4*i+2], k2[4*i+3]);
  }
  #pragma unroll
  for (int d = 0; d < 14; d++) {
    VhiT[(size_t)d * NN + r] = bf_hi(v[d]);
    VloT[(size_t)d * NN + r] = bf_hi(v[d] - bf_hi_f(v[d]));
  }
  VhiT[(size_t)14 * NN + r] = 0x3F80;  // bf16 1.0 -> ones column = softmax denom
  VhiT[(size_t)15 * NN + r] = 0;
  VloT[(size_t)14 * NN + r] = 0;
  VloT[(size_t)15 * NN + r] = 0;
}

// ------- MFMA attention phase 1 -------
__global__ __launch_bounds__(256, 4) void attn_mfma(
    const unsigned int* __restrict__ Qpack, const unsigned int* __restrict__ KB1,
    const unsigned int* __restrict__ KB2, const unsigned short* __restrict__ VhiT,
    const unsigned short* __restrict__ VloT, float* __restrict__ part) {
  __shared__ float Plds[4][16][36];
  const int tid = threadIdx.x;
  const int wave = tid >> 6;
  const int lane = tid & 63;
  const int lo4 = lane & 15;
  const int hi4 = lane >> 4;
  const int qbase = blockIdx.x * 128 + wave * 32;
  const int kbase0 = blockIdx.y * 256;

  const bf16x8* Qp = (const bf16x8*)Qpack;
  const bf16x8* B1 = (const bf16x8*)KB1;
  const bf16x8* B2 = (const bf16x8*)KB2;
  const bf16x8* Vh = (const bf16x8*)VhiT;
  const bf16x8* Vl = (const bf16x8*)VloT;

  bf16x8 aQ0 = Qp[(size_t)(qbase + lo4) * 4 + hi4];
  bf16x8 aQ1 = Qp[(size_t)(qbase + 16 + lo4) * 4 + hi4];
  f32x4 acc0 = {0.f, 0.f, 0.f, 0.f};
  f32x4 acc1 = {0.f, 0.f, 0.f, 0.f};
  const f32x4 zero = {0.f, 0.f, 0.f, 0.f};

  for (int c = 0; c < 8; c++) {
    const int kb = kbase0 + c * 32;
    bf16x8 b1g0 = B1[(size_t)(kb + lo4) * 4 + hi4];
    bf16x8 b2g0 = B2[(size_t)(kb + lo4) * 4 + hi4];
    bf16x8 b1g1 = B1[(size_t)(kb + 16 + lo4) * 4 + hi4];
    bf16x8 b2g1 = B2[(size_t)(kb + 16 + lo4) * 4 + hi4];
    bf16x8 vh = Vh[(size_t)lo4 * 1024 + (kb >> 3) + hi4];
    bf16x8 vl = Vl[(size_t)lo4 * 1024 + (kb >> 3) + hi4];

    #pragma unroll
    for (int sub = 0; sub < 2; sub++) {
      bf16x8 aQ = sub ? aQ1 : aQ0;
      f32x4 s0 = __builtin_amdgcn_mfma_f32_16x16x32_bf16(aQ, b1g0, zero, 0, 0, 0);
      s0 = __builtin_amdgcn_mfma_f32_16x16x32_bf16(aQ, b2g0, s0, 0, 0, 0);
      f32x4 s1 = __builtin_amdgcn_mfma_f32_16x16x32_bf16(aQ, b1g1, zero, 0, 0, 0);
      s1 = __builtin_amdgcn_mfma_f32_16x16x32_bf16(aQ, b2g1, s1, 0, 0, 0);
      #pragma unroll
      for (int reg = 0; reg < 4; reg++) {
        Plds[wave][hi4 * 4 + reg][lo4]      = fast_exp2(s0[reg]);
        Plds[wave][hi4 * 4 + reg][16 + lo4] = fast_exp2(s1[reg]);
      }
      __asm__ volatile("s_waitcnt lgkmcnt(0)" ::: "memory");
      const float4* pr = (const float4*)&Plds[wave][lo4][hi4 * 8];
      float4 f0 = pr[0];
      float4 f1 = pr[1];
      float pv[8] = {f0.x, f0.y, f0.z, f0.w, f1.x, f1.y, f1.z, f1.w};
      bf16x8 ph, pl;
      #pragma unroll
      for (int i = 0; i < 8; i++) {
        unsigned int u = __float_as_uint(pv[i]);
        ph[i] = (short)(u >> 16);
        float rr = pv[i] - __uint_as_float(u & 0xffff0000u);
        pl[i] = (short)(__float_as_uint(rr) >> 16);
      }
      f32x4 acc = sub ? acc1 : acc0;
      acc = __builtin_amdgcn_mfma_f32_16x16x32_bf16(ph, vh, acc, 0, 0, 0);
      acc = __builtin_amdgcn_mfma_f32_16x16x32_bf16(pl, vh, acc, 0, 0, 0);
      acc = __builtin_amdgcn_mfma_f32_16x16x32_bf16(ph, vl, acc, 0, 0, 0);
      if (sub) acc1 = acc; else acc0 = acc;
      __asm__ volatile("s_waitcnt lgkmcnt(0)" ::: "memory");
    }
  }
  float* pbase = part + (size_t)blockIdx.y * NN * 16;
  #pragma unroll
  for (int reg = 0; reg < 4; reg++) {
    int row0 = qbase + hi4 * 4 + reg;
    pbase[(size_t)row0 * 16 + lo4] = acc0[reg];
    pbase[(size_t)(row0 + 16) * 16 + lo4] = acc1[reg];
  }
}

// ---- attention combine + out-proj + residual + LN1 (l at col 14) ----
__global__ void attn_combine_ln1(float* __restrict__ h, const float* __restrict__ part,
                                 const float* __restrict__ wo, const float* __restrict__ bo,
                                 const float* __restrict__ g, const float* __restrict__ b) {
  int r = blockIdx.x * 256 + threadIdx.x;
  float L = 0.f;
  float A[14];
  #pragma unroll
  for (int d = 0; d < 14; d++) A[d] = 0.f;
  for (int c = 0; c < NCH; c++) {
    float p[16];
    LOAD16(p, part + ((size_t)c * NN + r) * 16);
    L += p[14];
    #pragma unroll
    for (int d = 0; d < 14; d++) A[d] += p[d];
  }
  float inv = 1.f / L;
  float a[14];
  #pragma unroll
  for (int d = 0; d < 14; d++) a[d] = A[d] * inv;
  float hr[16];
  LOAD16(hr, h + (size_t)r * DP);
  float xx[14];
  #pragma unroll
  for (int i = 0; i < 14; i++) {
    float s = bo[i];
    #pragma unroll
    for (int d = 0; d < 14; d++) s = fmaf(wo[i * 14 + d], a[d], s);
    xx[i] = hr[i] + s;
  }
  float mu = 0.f;
  #pragma unroll
  for (int i = 0; i < 14; i++) mu += xx[i];
  mu *= (1.f / 14.f);
  float var = 0.f;
  #pragma unroll
  for (int i = 0; i < 14; i++) { float t = xx[i] - mu; var = fmaf(t, t, var); }
  var *= (1.f / 14.f);
  float rs = rsqrtf(var + LN_EPS);
  float o[16];
  #pragma unroll
  for (int i = 0; i < 14; i++) o[i] = fmaf((xx[i] - mu) * rs, g[i], b[i]);
  o[14] = 0.f; o[15] = 0.f;
  STORE16(h + (size_t)r * DP, o);
}

// ---------------- fused FFN phase 1 (partials over j-chunks, 1 row/thread) --------
__global__ __launch_bounds__(256, 4) void ffn_phase1(
    const float* __restrict__ h, const float* __restrict__ w1,
    const float* __restrict__ b1, const float* __restrict__ w2,
    float* __restrict__ part) {
  __shared__ float W1s[FCH][16];
  __shared__ float W2s[FCH][16];
  __shared__ float b1s[FCH];
  const int tid = threadIdx.x;
  const int jbase = blockIdx.y * FCH;
  for (int idx = tid; idx < FCH * 16; idx += 256) {
    int j = idx >> 4, d = idx & 15;
    W1s[j][d] = (d < 14) ? w1[(size_t)(jbase + j) * 14 + d] : 0.f;
    W2s[j][d] = (d < 14) ? w2[(size_t)d * FF + jbase + j] : 0.f;
  }
  if (tid < FCH) b1s[tid] = b1[jbase + tid];
  __syncthreads();
  const int r = blockIdx.x * 256 + tid;
  float hr[16];
  LOAD16(hr, h + (size_t)r * DP);
  float a[14];
  #pragma unroll
  for (int d = 0; d < 14; d++) a[d] = 0.f;
  #pragma unroll 2
  for (int j = 0; j < FCH; j++) {
    float w1v[16];
    LOAD16(w1v, &W1s[j][0]);
    float s0 = 0.f, s1 = 0.f, s2 = 0.f, s3 = 0.f;
    #pragma unroll
    for (int d = 0; d < 4; d++) {
      s0 = fmaf(hr[d],      w1v[d],      s0);
      s1 = fmaf(hr[d + 4],  w1v[d + 4],  s1);
      s2 = fmaf(hr[d + 8],  w1v[d + 8],  s2);
      s3 = fmaf(hr[d + 12], w1v[d + 12], s3);
    }
    float t = fmaxf(((s0 + s1) + (s2 + s3)) + b1s[j], 0.f);
    float w2v[16];
    LOAD16(w2v, &W2s[j][0]);
    #pragma unroll
    for (int d = 0; d < 14; d++) a[d] = fmaf(t, w2v[d], a[d]);
  }
  float o[16];
  #pragma unroll
  for (int d = 0; d < 14; d++) o[d] = a[d];
  o[14] = 0.f; o[15] = 0.f;
  STORE16(part + ((size_t)blockIdx.y * NN + r) * 16, o);
}

// ---------------- FFN combine + residual + LN2 ----------------
__global__ void ffn_combine_ln2(float* __restrict__ h, const float* __restrict__ part,
                                const float* __restrict__ b2, const float* __restrict__ g,
                                const float* __restrict__ b) {
  int r = blockIdx.x * 256 + threadIdx.x;
  float f[14];
  #pragma unroll
  for (int d = 0; d < 14; d++) f[d] = b2[d];
  for (int c = 0; c < NFCH; c++) {
    float p[16];
    LOAD16(p, part + ((size_t)c * NN + r) * 16);
    #pragma unroll
    for (int d = 0; d < 14; d++) f[d] += p[d];
  }
  float hr[16];
  LOAD16(hr, h + (size_t)r * DP);
  float xx[14];
  #pragma unroll
  for (int i = 0; i < 14; i++) xx[i] = hr[i] + f[i];
  float mu = 0.f;
  #pragma unroll
  for (int i = 0; i < 14; i++) mu += xx[i];
  mu *= (1.f / 14.f);
  float var = 0.f;
  #pragma unroll
  for (int i = 0; i < 14; i++) { float t = xx[i] - mu; var = fmaf(t, t, var); }
  var *= (1.f / 14.f);
  float rs = rsqrtf(var + LN_EPS);
  float o[16];
  #pragma unroll
  for (int i = 0; i < 14; i++) o[i] = fmaf((xx[i] - mu) * rs, g[i], b[i]);
  o[14] = 0.f; o[15] = 0.f;
  STORE16(h + (size_t)r * DP, o);
}

// ---------------- size head: fc1 -> fc2 -> size_out ----------------
__global__ void head_size(const float* __restrict__ h, const float* __restrict__ fc1w,
                          const float* __restrict__ fc1b, const float* __restrict__ fc2w,
                          const float* __restrict__ fc2b, float* __restrict__ out,
                          float* __restrict__ sizef) {
  int r = blockIdx.x * 256 + threadIdx.x;
  float hr[16];
  LOAD16(hr, h + (size_t)r * DP);
  float s = fc2b[0];
  #pragma unroll
  for (int i = 0; i < 14; i++) {
    float t = fc1b[i];
    #pragma unroll
    for (int d = 0; d < 14; d++) t = fmaf(fc1w[i * 14 + d], hr[d], t);
    s = fmaf(t, fc2w[i], s);
  }
  out[r] = s;
  int si = (int)s;  // trunc toward zero, matches astype(int32)
  sizef[r] = (float)si;
}

// ---------------- regression head via MFMA (split-bf16, 3-pass) ----------------
// Block = 16 rows, 4 waves; wave w covers output neurons [64w, 64w+64).
__global__ __launch_bounds__(256, 4) void head_reg_mfma(
    const float* __restrict__ x, const float* __restrict__ y,
    const float* __restrict__ sizef,
    const unsigned short* __restrict__ B3h, const unsigned short* __restrict__ B3l,
    const float* __restrict__ b3,
    const unsigned short* __restrict__ B4h, const unsigned short* __restrict__ B4l,
    const float* __restrict__ b4,
    const float* __restrict__ w5, const float* __restrict__ b5,
    float* __restrict__ outr) {
  __shared__ alignas(16) unsigned short Ah[16][72], Al[16][72];      // reg_in hi/lo, K=64
  __shared__ alignas(16) unsigned short R1h[16][264], R1l[16][264];  // fc3 out hi/lo, K=256
  __shared__ float sred[4][16][16];
  const int tid = threadIdx.x;
  const int wave = tid >> 6;
  const int lane = tid & 63;
  const int lo4 = lane & 15;
  const int hi4 = lane >> 4;
  const int rbase = blockIdx.x * 16;

  // stage reg_in -> bf16 hi/lo in LDS (k >= 51 zero)
  for (int idx = tid; idx < 16 * 64; idx += 256) {
    int m = idx >> 6, k = idx & 63;
    int r = rbase + m;
    float v = 0.f;
    if (k == 0)       v = sizef[r];
    else if (k < 15)  v = x[(size_t)r * 14 + (k - 1)];
    else if (k < 51)  v = y[(size_t)r * 36 + (k - 15)];
    Ah[m][k] = bf_hi(v);
    Al[m][k] = bf_hi(v - bf_hi_f(v));
  }
  __syncthreads();

  const f32x4 zero = {0.f, 0.f, 0.f, 0.f};
  f32x4 acc[4];
  #pragma unroll
  for (int nt = 0; nt < 4; nt++) acc[nt] = zero;

  // fc3: M=16, N=64 (this wave), K=64
  #pragma unroll
  for (int ks = 0; ks < 2; ks++) {
    bf16x8 ah = *(const bf16x8*)&Ah[lo4][ks * 32 + hi4 * 8];
    bf16x8 al = *(const bf16x8*)&Al[lo4][ks * 32 + hi4 * 8];
    #pragma unroll
    for (int nt = 0; nt < 4; nt++) {
      int fi = ((wave * 4 + nt) * 2 + ks) * 64 + lane;
      bf16x8 bh = ((const bf16x8*)B3h)[fi];
      bf16x8 bl = ((const bf16x8*)B3l)[fi];
      acc[nt] = __builtin_amdgcn_mfma_f32_16x16x32_bf16(ah, bh, acc[nt], 0, 0, 0);
      acc[nt] = __builtin_amdgcn_mfma_f32_16x16x32_bf16(al, bh, acc[nt], 0, 0, 0);
      acc[nt] = __builtin_amdgcn_mfma_f32_16x16x32_bf16(ah, bl, acc[nt], 0, 0, 0);
    }
  }
  // relu + bias -> R1 (bf16 hi/lo); C-layout: m=hi4*4+reg, n=(wave*4+nt)*16+lo4
  #pragma unroll
  for (int nt = 0; nt < 4; nt++) {
    int n = (wave * 4 + nt) * 16 + lo4;
    float bb = b3[n];
    #pragma unroll
    for (int reg = 0; reg < 4; reg++) {
      int m = hi4 * 4 + reg;
      float v = fmaxf(acc[nt][reg] + bb, 0.f);
      R1h[m][n] = bf_hi(v);
      R1l[m][n] = bf_hi(v - bf_hi_f(v));
    }
  }
  __syncthreads();

  // fc4: M=16, N=64 (this wave), K=256
  #pragma unroll
  for (int nt = 0; nt < 4; nt++) acc[nt] = zero;
  #pragma unroll
  for (int ks = 0; ks < 8; ks++) {
    bf16x8 ah = *(const bf16x8*)&R1h[lo4][ks * 32 + hi4 * 8];
    bf16x8 al = *(const bf16x8*)&R1l[lo4][ks * 32 + hi4 * 8];
    #pragma unroll
    for (int nt = 0; nt < 4; nt++) {
      int fi = ((wave * 4 + nt) * 8 + ks) * 64 + lane;
      bf16x8 bh = ((const bf16x8*)B4h)[fi];
      bf16x8 bl = ((const bf16x8*)B4l)[fi];
      acc[nt] = __builtin_amdgcn_mfma_f32_16x16x32_bf16(ah, bh, acc[nt], 0, 0, 0);
      acc[nt] = __builtin_amdgcn_mfma_f32_16x16x32_bf16(al, bh, acc[nt], 0, 0, 0);
      acc[nt] = __builtin_amdgcn_mfma_f32_16x16x32_bf16(ah, bl, acc[nt], 0, 0, 0);
    }
  }
  // fc5 partial: per-lane sum over its 4 n-columns
  float s[4] = {0.f, 0.f, 0.f, 0.f};
  #pragma unroll
  for (int nt = 0; nt < 4; nt++) {
    int n = (wave * 4 + nt) * 16 + lo4;
    float bb = b4[n], ww = w5[n];
    #pragma unroll
    for (int reg = 0; reg < 4; reg++)
      s[reg] = fmaf(fmaxf(acc[nt][reg] + bb, 0.f), ww, s[reg]);
  }
  #pragma unroll
  for (int reg = 0; reg < 4; reg++) sred[wave][hi4 * 4 + reg][lo4] = s[reg];
  __syncthreads();

  if (tid < 16) {
    float t = b5[0];
    #pragma unroll
    for (int w = 0; w < 4; w++) {
      const float4* p = (const float4*)&sred[w][tid][0];
      float4 a0 = p[0], a1 = p[1], a2 = p[2], a3 = p[3];
      t += ((a0.x + a0.y) + (a0.z + a0.w)) + ((a1.x + a1.y) + (a1.z + a1.w)) +
           ((a2.x + a2.y) + (a2.z + a2.w)) + ((a3.x + a3.y) + (a3.z + a3.w));
    }
    float sz = sizef[rbase + tid];
    outr[rbase + tid] = (sz != 0.f) ? t : 0.f;
  }
}

extern "C" void kernel_launch(void* const* d_in, const int* in_sizes, int n_in,
                              void* d_out, int out_size, void* d_ws, size_t ws_size,
                              hipStream_t stream) {
  const float* x    = (const float*)d_in[0];
  const float* y    = (const float*)d_in[1];
  const float* wqkv = (const float*)d_in[2];
  const float* bqkv = (const float*)d_in[3];
  const float* wo   = (const float*)d_in[4];
  const float* bo   = (const float*)d_in[5];
  const float* ln1g = (const float*)d_in[6];
  const float* ln1b = (const float*)d_in[7];
  const float* ffw1 = (const float*)d_in[8];
  const float* ffb1 = (const float*)d_in[9];
  const float* ffw2 = (const float*)d_in[10];
  const float* ffb2 = (const float*)d_in[11];
  const float* ln2g = (const float*)d_in[12];
  const float* ln2b = (const float*)d_in[13];
  const float* fc1w = (const float*)d_in[14];
  const float* fc1b = (const float*)d_in[15];
  const float* fc2w = (const float*)d_in[16];
  const float* fc2b = (const float*)d_in[17];
  const float* fc3w = (const float*)d_in[18];
  const float* fc3b = (const float*)d_in[19];
  const float* fc4w = (const float*)d_in[20];
  const float* fc4b = (const float*)d_in[21];
  const float* fc5w = (const float*)d_in[22];
  const float* fc5b = (const float*)d_in[23];

  float* ws = (float*)d_ws;
  float* h     = ws;                        // 131072 floats
  unsigned int*   Qpack = (unsigned int*)(ws + 131072);
  unsigned int*   KB1   = (unsigned int*)(ws + 262144);
  unsigned int*   KB2   = (unsigned int*)(ws + 393216);
  unsigned short* VhiT  = (unsigned short*)(ws + 524288);
  unsigned short* VloT  = (unsigned short*)(ws + 589824);
  float* part  = ws + 655360;               // 32*8192*16 = 4194304 floats
  float* sizef = ws + 655360 + 4194304;     // 8192
  unsigned short* B3h = (unsigned short*)(ws + 4857856);   // 16384 ushorts
  unsigned short* B3l = (unsigned short*)(ws + 4866048);
  unsigned short* B4h = (unsigned short*)(ws + 4874240);   // 65536 ushorts
  unsigned short* B4l = (unsigned short*)(ws + 4907008);

  float* out = (float*)d_out;

  pack_head<<<32, 256, 0, stream>>>(fc3w, fc4w, B3h, B3l, B4h, B4l);
  copy_x<<<32, 256, 0, stream>>>(x, h);
  for (int l = 0; l < 2; l++) {
    qkv_pack<<<32, 256, 0, stream>>>(h, wqkv + (size_t)l * 42 * 14, bqkv + (size_t)l * 42,
                                     Qpack, KB1, KB2, VhiT, VloT);
    attn_mfma<<<dim3(64, NCH), 256, 0, stream>>>(Qpack, KB1, KB2, VhiT, VloT, part);
    attn_combine_ln1<<<32, 256, 0, stream>>>(h, part, wo + (size_t)l * 196,
                                             bo + (size_t)l * 14, ln1g + (size_t)l * 14,
                                             ln1b + (size_t)l * 14);
    ffn_phase1<<<dim3(32, NFCH), 256, 0, stream>>>(h, ffw1 + (size_t)l * FF * 14,
                                                   ffb1 + (size_t)l * FF,
                                                   ffw2 + (size_t)l * 14 * FF, part);
    ffn_combine_ln2<<<32, 256, 0, stream>>>(h, part, ffb2 + (size_t)l * 14,
                                            ln2g + (size_t)l * 14, ln2b + (size_t)l * 14);
  }
  head_size<<<32, 256, 0, stream>>>(h, fc1w, fc1b, fc2w, fc2b, out, sizef);
  head_reg_mfma<<<512, 256, 0, stream>>>(x, y, sizef, B3h, B3l, fc3b, B4h, B4l, fc4b,
                                         fc5w, fc5b, out + NN);
}

// Round 6
// 261.571 us; speedup vs baseline: 7.6742x; 1.2568x over previous
//
#include <hip/hip_runtime.h>
#include <math.h>

#define NN 8192
#define DD 14
#define DP 16
#define FF 2048
#define HID 256
#define LN_EPS 1e-5f
#define NCH 16      // attention key chunks (512 keys each)
#define NFCH 8      // ffn neuron chunks (256 each)
#define QSCALE (1.4426950408889634f / 3.7416573867739413f)  // log2(e)/sqrt(14)

typedef short bf16x8 __attribute__((ext_vector_type(8)));
typedef float f32x4 __attribute__((ext_vector_type(4)));

#define LOAD16(dst, srcp) { \
  const float4* _p = (const float4*)(srcp); \
  float4 _a = _p[0], _b = _p[1], _c = _p[2], _d = _p[3]; \
  dst[0]=_a.x; dst[1]=_a.y; dst[2]=_a.z; dst[3]=_a.w; \
  dst[4]=_b.x; dst[5]=_b.y; dst[6]=_b.z; dst[7]=_b.w; \
  dst[8]=_c.x; dst[9]=_c.y; dst[10]=_c.z; dst[11]=_c.w; \
  dst[12]=_d.x; dst[13]=_d.y; dst[14]=_d.z; dst[15]=_d.w; }

#define STORE16(dstp, src) { \
  float4* _p = (float4*)(dstp); \
  _p[0] = make_float4(src[0], src[1], src[2], src[3]); \
  _p[1] = make_float4(src[4], src[5], src[6], src[7]); \
  _p[2] = make_float4(src[8], src[9], src[10], src[11]); \
  _p[3] = make_float4(src[12], src[13], src[14], src[15]); }

static __device__ __forceinline__ float fast_exp2(float x) {
#if __has_builtin(__builtin_amdgcn_exp2f)
  return __builtin_amdgcn_exp2f(x);
#else
  return exp2f(x);
#endif
}

static __device__ __forceinline__ unsigned short bf_hi(float x) {
  return (unsigned short)(__float_as_uint(x) >> 16);
}
static __device__ __forceinline__ float bf_hi_f(float x) {
  return __uint_as_float(__float_as_uint(x) & 0xffff0000u);
}

// ---- shared helper: compute qkv for row r from hr[16], store packed operands ----
static __device__ __forceinline__ void qkv_compute_store(
    int r, const float* hr, const float* __restrict__ wqkv,
    const float* __restrict__ bqkv, unsigned int* __restrict__ Qpack,
    unsigned int* __restrict__ KB1, unsigned int* __restrict__ KB2,
    unsigned short* __restrict__ VhiT, unsigned short* __restrict__ VloT) {
  float q[14], k[14], v[14];
  #pragma unroll 6
  for (int c = 0; c < 42; c++) {
    const float* w = wqkv + c * 14;
    float s = bqkv[c];
    #pragma unroll
    for (int d = 0; d < 14; d++) s = fmaf(hr[d], w[d], s);
    if (c < 14)       q[c] = s * QSCALE;
    else if (c < 28)  k[c - 14] = s;
    else              v[c - 28] = s;
  }
  unsigned int qp[16], k1[16], k2[16];
  unsigned short qh[14], ql[14], kh[14], kl[14];
  #pragma unroll
  for (int d = 0; d < 14; d++) {
    qh[d] = bf_hi(q[d]);
    ql[d] = bf_hi(q[d] - bf_hi_f(q[d]));
    kh[d] = bf_hi(k[d]);
    kl[d] = bf_hi(k[d] - bf_hi_f(k[d]));
  }
  #pragma unroll
  for (int i = 0; i < 7; i++) {
    qp[i]     = (unsigned int)qh[2*i] | ((unsigned int)qh[2*i+1] << 16);
    qp[8 + i] = (unsigned int)ql[2*i] | ((unsigned int)ql[2*i+1] << 16);
    k1[i]     = (unsigned int)kh[2*i] | ((unsigned int)kh[2*i+1] << 16);
    k1[8 + i] = k1[i];
    k2[i]     = (unsigned int)kl[2*i] | ((unsigned int)kl[2*i+1] << 16);
    k2[8 + i] = k2[i];
  }
  qp[7] = 0; qp[15] = 0; k1[7] = 0; k1[15] = 0; k2[7] = 0; k2[15] = 0;
  uint4* Qp4 = (uint4*)(Qpack + (size_t)r * 16);
  uint4* K14 = (uint4*)(KB1 + (size_t)r * 16);
  uint4* K24 = (uint4*)(KB2 + (size_t)r * 16);
  #pragma unroll
  for (int i = 0; i < 4; i++) {
    Qp4[i] = make_uint4(qp[4*i], qp[4*i+1], qp[4*i+2], qp[4*i+3]);
    K14[i] = make_uint4(k1[4*i], k1[4*i+1], k1[4*i+2], k1[4*i+3]);
    K24[i] = make_uint4(k2[4*i], k2[4*i+1], k2[4*i+2], k2[4*i+3]);
  }
  #pragma unroll
  for (int d = 0; d < 14; d++) {
    VhiT[(size_t)d * NN + r] = bf_hi(v[d]);
    VloT[(size_t)d * NN + r] = bf_hi(v[d] - bf_hi_f(v[d]));
  }
  VhiT[(size_t)14 * NN + r] = 0x3F80;  // ones column = softmax denom
  VhiT[(size_t)15 * NN + r] = 0;
  VloT[(size_t)14 * NN + r] = 0;
  VloT[(size_t)15 * NN + r] = 0;
}

// ---- shared helper: A-operand pack of 14-dim vector (hi|lo) ----
static __device__ __forceinline__ void store_apack(unsigned int* dst, const float* o) {
  unsigned int qp[16];
  unsigned short hh[14], ll[14];
  #pragma unroll
  for (int d = 0; d < 14; d++) {
    hh[d] = bf_hi(o[d]);
    ll[d] = bf_hi(o[d] - bf_hi_f(o[d]));
  }
  #pragma unroll
  for (int i = 0; i < 7; i++) {
    qp[i]     = (unsigned int)hh[2*i] | ((unsigned int)hh[2*i+1] << 16);
    qp[8 + i] = (unsigned int)ll[2*i] | ((unsigned int)ll[2*i+1] << 16);
  }
  qp[7] = 0; qp[15] = 0;
  uint4* d4 = (uint4*)dst;
  #pragma unroll
  for (int i = 0; i < 4; i++)
    d4[i] = make_uint4(qp[4*i], qp[4*i+1], qp[4*i+2], qp[4*i+3]);
}

// ---- pack all static weights: fc3/fc4 B-frags + ffn w1 dup-packs + w2T hi/lo ----
__global__ void pack_weights(const float* __restrict__ w3, const float* __restrict__ w4,
                             const float* __restrict__ ffw1, const float* __restrict__ ffw2,
                             unsigned short* __restrict__ B3h, unsigned short* __restrict__ B3l,
                             unsigned short* __restrict__ B4h, unsigned short* __restrict__ B4l,
                             unsigned int* __restrict__ W1B1, unsigned int* __restrict__ W1B2,
                             unsigned short* __restrict__ W2h, unsigned short* __restrict__ W2l) {
  const int blk = blockIdx.x, tid = threadIdx.x;
  if (blk < 32) {
    int t = blk * 256 + tid;   // 0..8191
    int lane = t & 63, ks = (t >> 6) & 7, nt = t >> 9;
    int n = nt * 16 + (lane & 15);
    int k0 = ks * 32 + (lane >> 4) * 8;
    unsigned int h4[4], l4[4];
    #pragma unroll
    for (int jj = 0; jj < 4; jj++) {
      unsigned short h2[2], l2[2];
      #pragma unroll
      for (int e = 0; e < 2; e++) {
        float v = w4[(size_t)n * 256 + k0 + jj * 2 + e];
        h2[e] = bf_hi(v);
        l2[e] = bf_hi(v - bf_hi_f(v));
      }
      h4[jj] = (unsigned int)h2[0] | ((unsigned int)h2[1] << 16);
      l4[jj] = (unsigned int)l2[0] | ((unsigned int)l2[1] << 16);
    }
    ((uint4*)B4h)[t] = make_uint4(h4[0], h4[1], h4[2], h4[3]);
    ((uint4*)B4l)[t] = make_uint4(l4[0], l4[1], l4[2], l4[3]);
    if (ks < 2) {
      int fi = (nt * 2 + ks) * 64 + lane;
      #pragma unroll
      for (int jj = 0; jj < 4; jj++) {
        unsigned short h2[2], l2[2];
        #pragma unroll
        for (int e = 0; e < 2; e++) {
          int k = k0 + jj * 2 + e;
          float v = (k < 51) ? w3[(size_t)n * 51 + k] : 0.f;
          h2[e] = bf_hi(v);
          l2[e] = bf_hi(v - bf_hi_f(v));
        }
        h4[jj] = (unsigned int)h2[0] | ((unsigned int)h2[1] << 16);
        l4[jj] = (unsigned int)l2[0] | ((unsigned int)l2[1] << 16);
      }
      ((uint4*)B3h)[fi] = make_uint4(h4[0], h4[1], h4[2], h4[3]);
      ((uint4*)B3l)[fi] = make_uint4(l4[0], l4[1], l4[2], l4[3]);
    }
  } else if (blk < 48) {
    int t = (blk - 32) * 256 + tid;   // 0..4095: w1 dup-pack rows
    int l = t >> 11, j = t & 2047;
    const float* wrow = ffw1 + ((size_t)l * FF + j) * 14;
    unsigned int k1[16], k2[16];
    unsigned short kh[14], kl[14];
    #pragma unroll
    for (int d = 0; d < 14; d++) {
      float v = wrow[d];
      kh[d] = bf_hi(v);
      kl[d] = bf_hi(v - bf_hi_f(v));
    }
    #pragma unroll
    for (int i = 0; i < 7; i++) {
      k1[i] = (unsigned int)kh[2*i] | ((unsigned int)kh[2*i+1] << 16);
      k1[8 + i] = k1[i];
      k2[i] = (unsigned int)kl[2*i] | ((unsigned int)kl[2*i+1] << 16);
      k2[8 + i] = k2[i];
    }
    k1[7] = 0; k1[15] = 0; k2[7] = 0; k2[15] = 0;
    uint4* d1 = (uint4*)(W1B1 + (size_t)t * 16);
    uint4* d2 = (uint4*)(W1B2 + (size_t)t * 16);
    #pragma unroll
    for (int i = 0; i < 4; i++) {
      d1[i] = make_uint4(k1[4*i], k1[4*i+1], k1[4*i+2], k1[4*i+3]);
      d2[i] = make_uint4(k2[4*i], k2[4*i+1], k2[4*i+2], k2[4*i+3]);
    }
  } else {
    int t = (blk - 48) * 256 + tid;   // 0..4095: w2T hi/lo
    int l = t >> 11, j = t & 2047;
    #pragma unroll
    for (int d = 0; d < 16; d++) {
      float v = (d < 14) ? ffw2[((size_t)l * 14 + d) * FF + j] : 0.f;
      W2h[((size_t)l * 16 + d) * FF + j] = bf_hi(v);
      W2l[((size_t)l * 16 + d) * FF + j] = bf_hi(v - bf_hi_f(v));
    }
  }
}

// ---- layer-0 qkv: read x (stride 14), write padded h + qkv packs ----
__global__ void qkv_pack_x(const float* __restrict__ x, const float* __restrict__ wqkv,
                           const float* __restrict__ bqkv, float* __restrict__ h,
                           unsigned int* __restrict__ Qpack,
                           unsigned int* __restrict__ KB1, unsigned int* __restrict__ KB2,
                           unsigned short* __restrict__ VhiT,
                           unsigned short* __restrict__ VloT) {
  int r = blockIdx.x * 64 + threadIdx.x;
  float hr[16];
  #pragma unroll
  for (int d = 0; d < 14; d++) hr[d] = x[(size_t)r * 14 + d];
  hr[14] = 0.f; hr[15] = 0.f;
  STORE16(h + (size_t)r * DP, hr);
  qkv_compute_store(r, hr, wqkv, bqkv, Qpack, KB1, KB2, VhiT, VloT);
}

// ------- MFMA attention phase 1: 512 keys/chunk, partials -------
__global__ __launch_bounds__(256, 4) void attn_mfma(
    const unsigned int* __restrict__ Qpack, const unsigned int* __restrict__ KB1,
    const unsigned int* __restrict__ KB2, const unsigned short* __restrict__ VhiT,
    const unsigned short* __restrict__ VloT, float* __restrict__ part) {
  __shared__ float Plds[4][16][36];
  const int tid = threadIdx.x;
  const int wave = tid >> 6;
  const int lane = tid & 63;
  const int lo4 = lane & 15;
  const int hi4 = lane >> 4;
  const int qbase = blockIdx.x * 128 + wave * 32;
  const int kbase0 = blockIdx.y * 512;

  const bf16x8* Qp = (const bf16x8*)Qpack;
  const bf16x8* B1 = (const bf16x8*)KB1;
  const bf16x8* B2 = (const bf16x8*)KB2;
  const bf16x8* Vh = (const bf16x8*)VhiT;
  const bf16x8* Vl = (const bf16x8*)VloT;

  bf16x8 aQ0 = Qp[(size_t)(qbase + lo4) * 4 + hi4];
  bf16x8 aQ1 = Qp[(size_t)(qbase + 16 + lo4) * 4 + hi4];
  f32x4 acc0 = {0.f, 0.f, 0.f, 0.f};
  f32x4 acc1 = {0.f, 0.f, 0.f, 0.f};
  const f32x4 zero = {0.f, 0.f, 0.f, 0.f};

  for (int c = 0; c < 16; c++) {
    const int kb = kbase0 + c * 32;
    bf16x8 b1g0 = B1[(size_t)(kb + lo4) * 4 + hi4];
    bf16x8 b2g0 = B2[(size_t)(kb + lo4) * 4 + hi4];
    bf16x8 b1g1 = B1[(size_t)(kb + 16 + lo4) * 4 + hi4];
    bf16x8 b2g1 = B2[(size_t)(kb + 16 + lo4) * 4 + hi4];
    bf16x8 vh = Vh[(size_t)lo4 * 1024 + (kb >> 3) + hi4];
    bf16x8 vl = Vl[(size_t)lo4 * 1024 + (kb >> 3) + hi4];

    #pragma unroll
    for (int sub = 0; sub < 2; sub++) {
      bf16x8 aQ = sub ? aQ1 : aQ0;
      f32x4 s0 = __builtin_amdgcn_mfma_f32_16x16x32_bf16(aQ, b1g0, zero, 0, 0, 0);
      s0 = __builtin_amdgcn_mfma_f32_16x16x32_bf16(aQ, b2g0, s0, 0, 0, 0);
      f32x4 s1 = __builtin_amdgcn_mfma_f32_16x16x32_bf16(aQ, b1g1, zero, 0, 0, 0);
      s1 = __builtin_amdgcn_mfma_f32_16x16x32_bf16(aQ, b2g1, s1, 0, 0, 0);
      #pragma unroll
      for (int reg = 0; reg < 4; reg++) {
        Plds[wave][hi4 * 4 + reg][lo4]      = fast_exp2(s0[reg]);
        Plds[wave][hi4 * 4 + reg][16 + lo4] = fast_exp2(s1[reg]);
      }
      __asm__ volatile("s_waitcnt lgkmcnt(0)" ::: "memory");
      const float4* pr = (const float4*)&Plds[wave][lo4][hi4 * 8];
      float4 f0 = pr[0];
      float4 f1 = pr[1];
      float pv[8] = {f0.x, f0.y, f0.z, f0.w, f1.x, f1.y, f1.z, f1.w};
      bf16x8 ph, pl;
      #pragma unroll
      for (int i = 0; i < 8; i++) {
        unsigned int u = __float_as_uint(pv[i]);
        ph[i] = (short)(u >> 16);
        float rr = pv[i] - __uint_as_float(u & 0xffff0000u);
        pl[i] = (short)(__float_as_uint(rr) >> 16);
      }
      f32x4 acc = sub ? acc1 : acc0;
      acc = __builtin_amdgcn_mfma_f32_16x16x32_bf16(ph, vh, acc, 0, 0, 0);
      acc = __builtin_amdgcn_mfma_f32_16x16x32_bf16(pl, vh, acc, 0, 0, 0);
      acc = __builtin_amdgcn_mfma_f32_16x16x32_bf16(ph, vl, acc, 0, 0, 0);
      if (sub) acc1 = acc; else acc0 = acc;
      __asm__ volatile("s_waitcnt lgkmcnt(0)" ::: "memory");
    }
  }
  float* pbase = part + (size_t)blockIdx.y * NN * 16;
  #pragma unroll
  for (int reg = 0; reg < 4; reg++) {
    int row0 = qbase + hi4 * 4 + reg;
    pbase[(size_t)row0 * 16 + lo4] = acc0[reg];
    pbase[(size_t)(row0 + 16) * 16 + lo4] = acc1[reg];
  }
}

// ---- attention combine + out-proj + residual + LN1; writes h + Hpack ----
__global__ void attn_comb_ln1(float* __restrict__ h, const float* __restrict__ part,
                              const float* __restrict__ wo, const float* __restrict__ bo,
                              const float* __restrict__ g, const float* __restrict__ b,
                              unsigned int* __restrict__ Hpack) {
  int r = blockIdx.x * 64 + threadIdx.x;
  float L = 0.f;
  float A[14];
  #pragma unroll
  for (int d = 0; d < 14; d++) A[d] = 0.f;
  for (int c = 0; c < NCH; c++) {
    float p[16];
    LOAD16(p, part + ((size_t)c * NN + r) * 16);
    L += p[14];
    #pragma unroll
    for (int d = 0; d < 14; d++) A[d] += p[d];
  }
  float inv = 1.f / L;
  float a[14];
  #pragma unroll
  for (int d = 0; d < 14; d++) a[d] = A[d] * inv;
  float hr[16];
  LOAD16(hr, h + (size_t)r * DP);
  float xx[14];
  #pragma unroll
  for (int i = 0; i < 14; i++) {
    float s = bo[i];
    #pragma unroll
    for (int d = 0; d < 14; d++) s = fmaf(wo[i * 14 + d], a[d], s);
    xx[i] = hr[i] + s;
  }
  float mu = 0.f;
  #pragma unroll
  for (int i = 0; i < 14; i++) mu += xx[i];
  mu *= (1.f / 14.f);
  float var = 0.f;
  #pragma unroll
  for (int i = 0; i < 14; i++) { float t = xx[i] - mu; var = fmaf(t, t, var); }
  var *= (1.f / 14.f);
  float rs = rsqrtf(var + LN_EPS);
  float o[16];
  #pragma unroll
  for (int i = 0; i < 14; i++) o[i] = fmaf((xx[i] - mu) * rs, g[i], b[i]);
  o[14] = 0.f; o[15] = 0.f;
  STORE16(h + (size_t)r * DP, o);
  store_apack(Hpack + (size_t)r * 16, o);
}

// ------- MFMA FFN phase 1: 256 neurons/chunk, partials (attn_mfma clone) -------
__global__ __launch_bounds__(256, 4) void ffn_mfma(
    const unsigned int* __restrict__ Hpack, const unsigned int* __restrict__ W1B1,
    const unsigned int* __restrict__ W1B2, const unsigned short* __restrict__ W2h,
    const unsigned short* __restrict__ W2l, const float* __restrict__ b1,
    float* __restrict__ part) {
  __shared__ float Plds[4][16][36];
  const int tid = threadIdx.x;
  const int wave = tid >> 6;
  const int lane = tid & 63;
  const int lo4 = lane & 15;
  const int hi4 = lane >> 4;
  const int qbase = blockIdx.x * 128 + wave * 32;
  const int jbase0 = blockIdx.y * 256;

  const bf16x8* Hp = (const bf16x8*)Hpack;
  const bf16x8* B1 = (const bf16x8*)W1B1;
  const bf16x8* B2 = (const bf16x8*)W1B2;
  const bf16x8* Vh = (const bf16x8*)W2h;   // [d][j] : d*256 + j/8
  const bf16x8* Vl = (const bf16x8*)W2l;

  bf16x8 aH0 = Hp[(size_t)(qbase + lo4) * 4 + hi4];
  bf16x8 aH1 = Hp[(size_t)(qbase + 16 + lo4) * 4 + hi4];
  f32x4 acc0 = {0.f, 0.f, 0.f, 0.f};
  f32x4 acc1 = {0.f, 0.f, 0.f, 0.f};
  const f32x4 zero = {0.f, 0.f, 0.f, 0.f};

  for (int c = 0; c < 8; c++) {
    const int jb = jbase0 + c * 32;
    bf16x8 b1g0 = B1[(size_t)(jb + lo4) * 4 + hi4];
    bf16x8 b2g0 = B2[(size_t)(jb + lo4) * 4 + hi4];
    bf16x8 b1g1 = B1[(size_t)(jb + 16 + lo4) * 4 + hi4];
    bf16x8 b2g1 = B2[(size_t)(jb + 16 + lo4) * 4 + hi4];
    bf16x8 vh = Vh[(size_t)lo4 * 256 + (jb >> 3) + hi4];
    bf16x8 vl = Vl[(size_t)lo4 * 256 + (jb >> 3) + hi4];
    float bb0 = b1[jb + lo4];
    float bb1 = b1[jb + 16 + lo4];

    #pragma unroll
    for (int sub = 0; sub < 2; sub++) {
      bf16x8 aH = sub ? aH1 : aH0;
      // S = h.w1^T exactly: (hhi+hlo)*(w1hi) + (hhi+hlo)*(w1lo)
      f32x4 s0 = __builtin_amdgcn_mfma_f32_16x16x32_bf16(aH, b1g0, zero, 0, 0, 0);
      s0 = __builtin_amdgcn_mfma_f32_16x16x32_bf16(aH, b2g0, s0, 0, 0, 0);
      f32x4 s1 = __builtin_amdgcn_mfma_f32_16x16x32_bf16(aH, b1g1, zero, 0, 0, 0);
      s1 = __builtin_amdgcn_mfma_f32_16x16x32_bf16(aH, b2g1, s1, 0, 0, 0);
      #pragma unroll
      for (int reg = 0; reg < 4; reg++) {
        Plds[wave][hi4 * 4 + reg][lo4]      = fmaxf(s0[reg] + bb0, 0.f);
        Plds[wave][hi4 * 4 + reg][16 + lo4] = fmaxf(s1[reg] + bb1, 0.f);
      }
      __asm__ volatile("s_waitcnt lgkmcnt(0)" ::: "memory");
      const float4* pr = (const float4*)&Plds[wave][lo4][hi4 * 8];
      float4 f0 = pr[0];
      float4 f1 = pr[1];
      float pv[8] = {f0.x, f0.y, f0.z, f0.w, f1.x, f1.y, f1.z, f1.w};
      bf16x8 th, tl;
      #pragma unroll
      for (int i = 0; i < 8; i++) {
        unsigned int u = __float_as_uint(pv[i]);
        th[i] = (short)(u >> 16);
        float rr = pv[i] - __uint_as_float(u & 0xffff0000u);
        tl[i] = (short)(__float_as_uint(rr) >> 16);
      }
      f32x4 acc = sub ? acc1 : acc0;
      acc = __builtin_amdgcn_mfma_f32_16x16x32_bf16(th, vh, acc, 0, 0, 0);
      acc = __builtin_amdgcn_mfma_f32_16x16x32_bf16(tl, vh, acc, 0, 0, 0);
      acc = __builtin_amdgcn_mfma_f32_16x16x32_bf16(th, vl, acc, 0, 0, 0);
      if (sub) acc1 = acc; else acc0 = acc;
      __asm__ volatile("s_waitcnt lgkmcnt(0)" ::: "memory");
    }
  }
  float* pbase = part + (size_t)blockIdx.y * NN * 16;
  #pragma unroll
  for (int reg = 0; reg < 4; reg++) {
    int row0 = qbase + hi4 * 4 + reg;
    pbase[(size_t)row0 * 16 + lo4] = acc0[reg];
    pbase[(size_t)(row0 + 16) * 16 + lo4] = acc1[reg];
  }
}

// ---- FFN combine + residual + LN2, then qkv packs for the NEXT layer ----
__global__ void ffn_ln2_qkv(float* __restrict__ h, const float* __restrict__ part,
                            const float* __restrict__ b2, const float* __restrict__ g,
                            const float* __restrict__ b,
                            const float* __restrict__ wqkv, const float* __restrict__ bqkv,
                            unsigned int* __restrict__ Qpack,
                            unsigned int* __restrict__ KB1, unsigned int* __restrict__ KB2,
                            unsigned short* __restrict__ VhiT,
                            unsigned short* __restrict__ VloT) {
  int r = blockIdx.x * 64 + threadIdx.x;
  float f[14];
  #pragma unroll
  for (int d = 0; d < 14; d++) f[d] = b2[d];
  for (int c = 0; c < NFCH; c++) {
    float p[16];
    LOAD16(p, part + ((size_t)c * NN + r) * 16);
    #pragma unroll
    for (int d = 0; d < 14; d++) f[d] += p[d];
  }
  float hr[16];
  LOAD16(hr, h + (size_t)r * DP);
  float xx[14];
  #pragma unroll
  for (int i = 0; i < 14; i++) xx[i] = hr[i] + f[i];
  float mu = 0.f;
  #pragma unroll
  for (int i = 0; i < 14; i++) mu += xx[i];
  mu *= (1.f / 14.f);
  float var = 0.f;
  #pragma unroll
  for (int i = 0; i < 14; i++) { float t = xx[i] - mu; var = fmaf(t, t, var); }
  var *= (1.f / 14.f);
  float rs = rsqrtf(var + LN_EPS);
  float o[16];
  #pragma unroll
  for (int i = 0; i < 14; i++) o[i] = fmaf((xx[i] - mu) * rs, g[i], b[i]);
  o[14] = 0.f; o[15] = 0.f;
  STORE16(h + (size_t)r * DP, o);
  qkv_compute_store(r, o, wqkv, bqkv, Qpack, KB1, KB2, VhiT, VloT);
}

// ---- final FFN combine + LN2 + size head (fc1->fc2) ----
__global__ void ffn_ln2_size(const float* __restrict__ h, const float* __restrict__ part,
                             const float* __restrict__ b2, const float* __restrict__ g,
                             const float* __restrict__ b,
                             const float* __restrict__ fc1w, const float* __restrict__ fc1b,
                             const float* __restrict__ fc2w, const float* __restrict__ fc2b,
                             float* __restrict__ out, float* __restrict__ sizef) {
  int r = blockIdx.x * 64 + threadIdx.x;
  float f[14];
  #pragma unroll
  for (int d = 0; d < 14; d++) f[d] = b2[d];
  for (int c = 0; c < NFCH; c++) {
    float p[16];
    LOAD16(p, part + ((size_t)c * NN + r) * 16);
    #pragma unroll
    for (int d = 0; d < 14; d++) f[d] += p[d];
  }
  float hr[16];
  LOAD16(hr, h + (size_t)r * DP);
  float xx[14];
  #pragma unroll
  for (int i = 0; i < 14; i++) xx[i] = hr[i] + f[i];
  float mu = 0.f;
  #pragma unroll
  for (int i = 0; i < 14; i++) mu += xx[i];
  mu *= (1.f / 14.f);
  float var = 0.f;
  #pragma unroll
  for (int i = 0; i < 14; i++) { float t = xx[i] - mu; var = fmaf(t, t, var); }
  var *= (1.f / 14.f);
  float rs = rsqrtf(var + LN_EPS);
  float o[14];
  #pragma unroll
  for (int i = 0; i < 14; i++) o[i] = fmaf((xx[i] - mu) * rs, g[i], b[i]);
  float s = fc2b[0];
  #pragma unroll
  for (int i = 0; i < 14; i++) {
    float t = fc1b[i];
    #pragma unroll
    for (int d = 0; d < 14; d++) t = fmaf(fc1w[i * 14 + d], o[d], t);
    s = fmaf(t, fc2w[i], s);
  }
  out[r] = s;
  int si = (int)s;  // trunc toward zero, matches astype(int32)
  sizef[r] = (float)si;
}

// ---------------- regression head via MFMA (split-bf16, 3-pass) ----------------
__global__ __launch_bounds__(256, 4) void head_reg_mfma(
    const float* __restrict__ x, const float* __restrict__ y,
    const float* __restrict__ sizef,
    const unsigned short* __restrict__ B3h, const unsigned short* __restrict__ B3l,
    const float* __restrict__ b3,
    const unsigned short* __restrict__ B4h, const unsigned short* __restrict__ B4l,
    const float* __restrict__ b4,
    const float* __restrict__ w5, const float* __restrict__ b5,
    float* __restrict__ outr) {
  __shared__ alignas(16) unsigned short Ah[16][72], Al[16][72];
  __shared__ alignas(16) unsigned short R1h[16][264], R1l[16][264];
  __shared__ float sred[4][16][16];
  const int tid = threadIdx.x;
  const int wave = tid >> 6;
  const int lane = tid & 63;
  const int lo4 = lane & 15;
  const int hi4 = lane >> 4;
  const int rbase = blockIdx.x * 16;

  for (int idx = tid; idx < 16 * 64; idx += 256) {
    int m = idx >> 6, k = idx & 63;
    int r = rbase + m;
    float v = 0.f;
    if (k == 0)       v = sizef[r];
    else if (k < 15)  v = x[(size_t)r * 14 + (k - 1)];
    else if (k < 51)  v = y[(size_t)r * 36 + (k - 15)];
    Ah[m][k] = bf_hi(v);
    Al[m][k] = bf_hi(v - bf_hi_f(v));
  }
  __syncthreads();

  const f32x4 zero = {0.f, 0.f, 0.f, 0.f};
  f32x4 acc[4];
  #pragma unroll
  for (int nt = 0; nt < 4; nt++) acc[nt] = zero;

  #pragma unroll
  for (int ks = 0; ks < 2; ks++) {
    bf16x8 ah = *(const bf16x8*)&Ah[lo4][ks * 32 + hi4 * 8];
    bf16x8 al = *(const bf16x8*)&Al[lo4][ks * 32 + hi4 * 8];
    #pragma unroll
    for (int nt = 0; nt < 4; nt++) {
      int fi = ((wave * 4 + nt) * 2 + ks) * 64 + lane;
      bf16x8 bh = ((const bf16x8*)B3h)[fi];
      bf16x8 bl = ((const bf16x8*)B3l)[fi];
      acc[nt] = __builtin_amdgcn_mfma_f32_16x16x32_bf16(ah, bh, acc[nt], 0, 0, 0);
      acc[nt] = __builtin_amdgcn_mfma_f32_16x16x32_bf16(al, bh, acc[nt], 0, 0, 0);
      acc[nt] = __builtin_amdgcn_mfma_f32_16x16x32_bf16(ah, bl, acc[nt], 0, 0, 0);
    }
  }
  #pragma unroll
  for (int nt = 0; nt < 4; nt++) {
    int n = (wave * 4 + nt) * 16 + lo4;
    float bb = b3[n];
    #pragma unroll
    for (int reg = 0; reg < 4; reg++) {
      int m = hi4 * 4 + reg;
      float v = fmaxf(acc[nt][reg] + bb, 0.f);
      R1h[m][n] = bf_hi(v);
      R1l[m][n] = bf_hi(v - bf_hi_f(v));
    }
  }
  __syncthreads();

  #pragma unroll
  for (int nt = 0; nt < 4; nt++) acc[nt] = zero;
  #pragma unroll
  for (int ks = 0; ks < 8; ks++) {
    bf16x8 ah = *(const bf16x8*)&R1h[lo4][ks * 32 + hi4 * 8];
    bf16x8 al = *(const bf16x8*)&R1l[lo4][ks * 32 + hi4 * 8];
    #pragma unroll
    for (int nt = 0; nt < 4; nt++) {
      int fi = ((wave * 4 + nt) * 8 + ks) * 64 + lane;
      bf16x8 bh = ((const bf16x8*)B4h)[fi];
      bf16x8 bl = ((const bf16x8*)B4l)[fi];
      acc[nt] = __builtin_amdgcn_mfma_f32_16x16x32_bf16(ah, bh, acc[nt], 0, 0, 0);
      acc[nt] = __builtin_amdgcn_mfma_f32_16x16x32_bf16(al, bh, acc[nt], 0, 0, 0);
      acc[nt] = __builtin_amdgcn_mfma_f32_16x16x32_bf16(ah, bl, acc[nt], 0, 0, 0);
    }
  }
  float s[4] = {0.f, 0.f, 0.f, 0.f};
  #pragma unroll
  for (int nt = 0; nt < 4; nt++) {
    int n = (wave * 4 + nt) * 16 + lo4;
    float bb = b4[n], ww = w5[n];
    #pragma unroll
    for (int reg = 0; reg < 4; reg++)
      s[reg] = fmaf(fmaxf(acc[nt][reg] + bb, 0.f), ww, s[reg]);
  }
  #pragma unroll
  for (int reg = 0; reg < 4; reg++) sred[wave][hi4 * 4 + reg][lo4] = s[reg];
  __syncthreads();

  if (tid < 16) {
    float t = b5[0];
    #pragma unroll
    for (int w = 0; w < 4; w++) {
      const float4* p = (const float4*)&sred[w][tid][0];
      float4 a0 = p[0], a1 = p[1], a2 = p[2], a3 = p[3];
      t += ((a0.x + a0.y) + (a0.z + a0.w)) + ((a1.x + a1.y) + (a1.z + a1.w)) +
           ((a2.x + a2.y) + (a2.z + a2.w)) + ((a3.x + a3.y) + (a3.z + a3.w));
    }
    float sz = sizef[rbase + tid];
    outr[rbase + tid] = (sz != 0.f) ? t : 0.f;
  }
}

extern "C" void kernel_launch(void* const* d_in, const int* in_sizes, int n_in,
                              void* d_out, int out_size, void* d_ws, size_t ws_size,
                              hipStream_t stream) {
  const float* x    = (const float*)d_in[0];
  const float* y    = (const float*)d_in[1];
  const float* wqkv = (const float*)d_in[2];
  const float* bqkv = (const float*)d_in[3];
  const float* wo   = (const float*)d_in[4];
  const float* bo   = (const float*)d_in[5];
  const float* ln1g = (const float*)d_in[6];
  const float* ln1b = (const float*)d_in[7];
  const float* ffw1 = (const float*)d_in[8];
  const float* ffb1 = (const float*)d_in[9];
  const float* ffw2 = (const float*)d_in[10];
  const float* ffb2 = (const float*)d_in[11];
  const float* ln2g = (const float*)d_in[12];
  const float* ln2b = (const float*)d_in[13];
  const float* fc1w = (const float*)d_in[14];
  const float* fc1b = (const float*)d_in[15];
  const float* fc2w = (const float*)d_in[16];
  const float* fc2b = (const float*)d_in[17];
  const float* fc3w = (const float*)d_in[18];
  const float* fc3b = (const float*)d_in[19];
  const float* fc4w = (const float*)d_in[20];
  const float* fc4b = (const float*)d_in[21];
  const float* fc5w = (const float*)d_in[22];
  const float* fc5b = (const float*)d_in[23];

  float* ws = (float*)d_ws;
  float*          h     = ws;                               // 131072
  unsigned int*   Qpack = (unsigned int*)(ws + 131072);     // 131072
  unsigned int*   KB1   = (unsigned int*)(ws + 262144);     // 131072
  unsigned int*   KB2   = (unsigned int*)(ws + 393216);     // 131072
  unsigned short* VhiT  = (unsigned short*)(ws + 524288);   // 65536 f
  unsigned short* VloT  = (unsigned short*)(ws + 589824);   // 65536 f
  unsigned int*   Hpack = (unsigned int*)(ws + 655360);     // 131072
  float*          part  = ws + 786432;                      // 16*8192*16 = 2097152
  float*          sizef = ws + 2883584;                     // 8192
  unsigned short* B3h   = (unsigned short*)(ws + 2891776);  // 8192 f
  unsigned short* B3l   = (unsigned short*)(ws + 2899968);
  unsigned short* B4h   = (unsigned short*)(ws + 2908160);  // 32768 f
  unsigned short* B4l   = (unsigned short*)(ws + 2940928);
  unsigned int*   W1B1  = (unsigned int*)(ws + 2973696);    // 65536
  unsigned int*   W1B2  = (unsigned int*)(ws + 3039232);
  unsigned short* W2h   = (unsigned short*)(ws + 3104768);  // 32768 f
  unsigned short* W2l   = (unsigned short*)(ws + 3137536);

  float* out = (float*)d_out;

  pack_weights<<<64, 256, 0, stream>>>(fc3w, fc4w, ffw1, ffw2, B3h, B3l, B4h, B4l,
                                       W1B1, W1B2, W2h, W2l);
  qkv_pack_x<<<128, 64, 0, stream>>>(x, wqkv, bqkv, h, Qpack, KB1, KB2, VhiT, VloT);
  for (int l = 0; l < 2; l++) {
    attn_mfma<<<dim3(64, NCH), 256, 0, stream>>>(Qpack, KB1, KB2, VhiT, VloT, part);
    attn_comb_ln1<<<128, 64, 0, stream>>>(h, part, wo + (size_t)l * 196,
                                          bo + (size_t)l * 14, ln1g + (size_t)l * 14,
                                          ln1b + (size_t)l * 14, Hpack);
    ffn_mfma<<<dim3(64, NFCH), 256, 0, stream>>>(
        Hpack, W1B1 + (size_t)l * 2048 * 16, W1B2 + (size_t)l * 2048 * 16,
        W2h + (size_t)l * 16 * FF, W2l + (size_t)l * 16 * FF,
        ffb1 + (size_t)l * FF, part);
    if (l == 0) {
      ffn_ln2_qkv<<<128, 64, 0, stream>>>(h, part, ffb2, ln2g, ln2b,
                                          wqkv + 42 * 14, bqkv + 42,
                                          Qpack, KB1, KB2, VhiT, VloT);
    } else {
      ffn_ln2_size<<<128, 64, 0, stream>>>(h, part, ffb2 + 14, ln2g + 14, ln2b + 14,
                                           fc1w, fc1b, fc2w, fc2b, out, sizef);
    }
  }
  head_reg_mfma<<<512, 256, 0, stream>>>(x, y, sizef, B3h, B3l, fc3b, B4h, B4l, fc4b,
                                         fc5w, fc5b, out + NN);
}

// Round 7
// 255.603 us; speedup vs baseline: 7.8534x; 1.0233x over previous
//
#include <hip/hip_runtime.h>
#include <math.h>

#define NN 8192
#define DD 14
#define DP 16
#define FF 2048
#define HID 256
#define LN_EPS 1e-5f
#define NCH 16      // attention key chunks (512 keys each)
#define NFCH 8      // ffn neuron chunks (256 each)
#define QSCALE (1.4426950408889634f / 3.7416573867739413f)  // log2(e)/sqrt(14)

typedef short bf16x8 __attribute__((ext_vector_type(8)));
typedef float f32x4 __attribute__((ext_vector_type(4)));

#define LOAD16(dst, srcp) { \
  const float4* _p = (const float4*)(srcp); \
  float4 _a = _p[0], _b = _p[1], _c = _p[2], _d = _p[3]; \
  dst[0]=_a.x; dst[1]=_a.y; dst[2]=_a.z; dst[3]=_a.w; \
  dst[4]=_b.x; dst[5]=_b.y; dst[6]=_b.z; dst[7]=_b.w; \
  dst[8]=_c.x; dst[9]=_c.y; dst[10]=_c.z; dst[11]=_c.w; \
  dst[12]=_d.x; dst[13]=_d.y; dst[14]=_d.z; dst[15]=_d.w; }

#define STORE16(dstp, src) { \
  float4* _p = (float4*)(dstp); \
  _p[0] = make_float4(src[0], src[1], src[2], src[3]); \
  _p[1] = make_float4(src[4], src[5], src[6], src[7]); \
  _p[2] = make_float4(src[8], src[9], src[10], src[11]); \
  _p[3] = make_float4(src[12], src[13], src[14], src[15]); }

static __device__ __forceinline__ float fast_exp2(float x) {
#if __has_builtin(__builtin_amdgcn_exp2f)
  return __builtin_amdgcn_exp2f(x);
#else
  return exp2f(x);
#endif
}

static __device__ __forceinline__ unsigned short bf_hi(float x) {
  return (unsigned short)(__float_as_uint(x) >> 16);
}
static __device__ __forceinline__ float bf_hi_f(float x) {
  return __uint_as_float(__float_as_uint(x) & 0xffff0000u);
}

// ---- repack 8 floats -> bf16 hi/lo fragments ----
static __device__ __forceinline__ void split8(const float* pv, bf16x8* ph, bf16x8* pl) {
  #pragma unroll
  for (int i = 0; i < 8; i++) {
    unsigned int u = __float_as_uint(pv[i]);
    (*ph)[i] = (short)(u >> 16);
    float rr = pv[i] - __uint_as_float(u & 0xffff0000u);
    (*pl)[i] = (short)(__float_as_uint(rr) >> 16);
  }
}

// ---- shared helper: compute qkv for row r from hr[16], store packed operands ----
static __device__ __forceinline__ void qkv_compute_store(
    int r, const float* hr, const float* __restrict__ wqkv,
    const float* __restrict__ bqkv, unsigned int* __restrict__ Qpack,
    unsigned int* __restrict__ KB1, unsigned int* __restrict__ KB2,
    unsigned short* __restrict__ VhiT, unsigned short* __restrict__ VloT) {
  float q[14], k[14], v[14];
  #pragma unroll 6
  for (int c = 0; c < 42; c++) {
    const float* w = wqkv + c * 14;
    float s = bqkv[c];
    #pragma unroll
    for (int d = 0; d < 14; d++) s = fmaf(hr[d], w[d], s);
    if (c < 14)       q[c] = s * QSCALE;
    else if (c < 28)  k[c - 14] = s;
    else              v[c - 28] = s;
  }
  unsigned int qp[16], k1[16], k2[16];
  unsigned short qh[14], ql[14], kh[14], kl[14];
  #pragma unroll
  for (int d = 0; d < 14; d++) {
    qh[d] = bf_hi(q[d]);
    ql[d] = bf_hi(q[d] - bf_hi_f(q[d]));
    kh[d] = bf_hi(k[d]);
    kl[d] = bf_hi(k[d] - bf_hi_f(k[d]));
  }
  #pragma unroll
  for (int i = 0; i < 7; i++) {
    qp[i]     = (unsigned int)qh[2*i] | ((unsigned int)qh[2*i+1] << 16);
    qp[8 + i] = (unsigned int)ql[2*i] | ((unsigned int)ql[2*i+1] << 16);
    k1[i]     = (unsigned int)kh[2*i] | ((unsigned int)kh[2*i+1] << 16);
    k1[8 + i] = k1[i];
    k2[i]     = (unsigned int)kl[2*i] | ((unsigned int)kl[2*i+1] << 16);
    k2[8 + i] = k2[i];
  }
  qp[7] = 0; qp[15] = 0; k1[7] = 0; k1[15] = 0; k2[7] = 0; k2[15] = 0;
  uint4* Qp4 = (uint4*)(Qpack + (size_t)r * 16);
  uint4* K14 = (uint4*)(KB1 + (size_t)r * 16);
  uint4* K24 = (uint4*)(KB2 + (size_t)r * 16);
  #pragma unroll
  for (int i = 0; i < 4; i++) {
    Qp4[i] = make_uint4(qp[4*i], qp[4*i+1], qp[4*i+2], qp[4*i+3]);
    K14[i] = make_uint4(k1[4*i], k1[4*i+1], k1[4*i+2], k1[4*i+3]);
    K24[i] = make_uint4(k2[4*i], k2[4*i+1], k2[4*i+2], k2[4*i+3]);
  }
  #pragma unroll
  for (int d = 0; d < 14; d++) {
    VhiT[(size_t)d * NN + r] = bf_hi(v[d]);
    VloT[(size_t)d * NN + r] = bf_hi(v[d] - bf_hi_f(v[d]));
  }
  VhiT[(size_t)14 * NN + r] = 0x3F80;  // ones column = softmax denom
  VhiT[(size_t)15 * NN + r] = 0;
  VloT[(size_t)14 * NN + r] = 0;
  VloT[(size_t)15 * NN + r] = 0;
}

// ---- shared helper: A-operand pack of 14-dim vector (hi|lo) ----
static __device__ __forceinline__ void store_apack(unsigned int* dst, const float* o) {
  unsigned int qp[16];
  unsigned short hh[14], ll[14];
  #pragma unroll
  for (int d = 0; d < 14; d++) {
    hh[d] = bf_hi(o[d]);
    ll[d] = bf_hi(o[d] - bf_hi_f(o[d]));
  }
  #pragma unroll
  for (int i = 0; i < 7; i++) {
    qp[i]     = (unsigned int)hh[2*i] | ((unsigned int)hh[2*i+1] << 16);
    qp[8 + i] = (unsigned int)ll[2*i] | ((unsigned int)ll[2*i+1] << 16);
  }
  qp[7] = 0; qp[15] = 0;
  uint4* d4 = (uint4*)dst;
  #pragma unroll
  for (int i = 0; i < 4; i++)
    d4[i] = make_uint4(qp[4*i], qp[4*i+1], qp[4*i+2], qp[4*i+3]);
}

// ---- one prep kernel: weight packs (fc3/fc4/ffn) + layer-0 qkv from x ----
__global__ void pack_all(const float* __restrict__ w3, const float* __restrict__ w4,
                         const float* __restrict__ ffw1, const float* __restrict__ ffw2,
                         const float* __restrict__ x, const float* __restrict__ wqkv,
                         const float* __restrict__ bqkv, float* __restrict__ h,
                         unsigned int* __restrict__ Qpack,
                         unsigned int* __restrict__ KB1, unsigned int* __restrict__ KB2,
                         unsigned short* __restrict__ VhiT, unsigned short* __restrict__ VloT,
                         unsigned short* __restrict__ B3h, unsigned short* __restrict__ B3l,
                         unsigned short* __restrict__ B4h, unsigned short* __restrict__ B4l,
                         unsigned int* __restrict__ W1B1, unsigned int* __restrict__ W1B2,
                         unsigned short* __restrict__ W2h, unsigned short* __restrict__ W2l) {
  const int blk = blockIdx.x, tid = threadIdx.x;
  if (blk < 32) {
    int t = blk * 256 + tid;   // 0..8191 : fc4 (+fc3) B-frags
    int lane = t & 63, ks = (t >> 6) & 7, nt = t >> 9;
    int n = nt * 16 + (lane & 15);
    int k0 = ks * 32 + (lane >> 4) * 8;
    unsigned int h4[4], l4[4];
    #pragma unroll
    for (int jj = 0; jj < 4; jj++) {
      unsigned short h2[2], l2[2];
      #pragma unroll
      for (int e = 0; e < 2; e++) {
        float v = w4[(size_t)n * 256 + k0 + jj * 2 + e];
        h2[e] = bf_hi(v);
        l2[e] = bf_hi(v - bf_hi_f(v));
      }
      h4[jj] = (unsigned int)h2[0] | ((unsigned int)h2[1] << 16);
      l4[jj] = (unsigned int)l2[0] | ((unsigned int)l2[1] << 16);
    }
    ((uint4*)B4h)[t] = make_uint4(h4[0], h4[1], h4[2], h4[3]);
    ((uint4*)B4l)[t] = make_uint4(l4[0], l4[1], l4[2], l4[3]);
    if (ks < 2) {
      int fi = (nt * 2 + ks) * 64 + lane;
      #pragma unroll
      for (int jj = 0; jj < 4; jj++) {
        unsigned short h2[2], l2[2];
        #pragma unroll
        for (int e = 0; e < 2; e++) {
          int k = k0 + jj * 2 + e;
          float v = (k < 51) ? w3[(size_t)n * 51 + k] : 0.f;
          h2[e] = bf_hi(v);
          l2[e] = bf_hi(v - bf_hi_f(v));
        }
        h4[jj] = (unsigned int)h2[0] | ((unsigned int)h2[1] << 16);
        l4[jj] = (unsigned int)l2[0] | ((unsigned int)l2[1] << 16);
      }
      ((uint4*)B3h)[fi] = make_uint4(h4[0], h4[1], h4[2], h4[3]);
      ((uint4*)B3l)[fi] = make_uint4(l4[0], l4[1], l4[2], l4[3]);
    }
  } else if (blk < 48) {
    int t = (blk - 32) * 256 + tid;   // 0..4095: w1 dup-pack rows
    int l = t >> 11, j = t & 2047;
    const float* wrow = ffw1 + ((size_t)l * FF + j) * 14;
    unsigned int k1[16], k2[16];
    unsigned short kh[14], kl[14];
    #pragma unroll
    for (int d = 0; d < 14; d++) {
      float v = wrow[d];
      kh[d] = bf_hi(v);
      kl[d] = bf_hi(v - bf_hi_f(v));
    }
    #pragma unroll
    for (int i = 0; i < 7; i++) {
      k1[i] = (unsigned int)kh[2*i] | ((unsigned int)kh[2*i+1] << 16);
      k1[8 + i] = k1[i];
      k2[i] = (unsigned int)kl[2*i] | ((unsigned int)kl[2*i+1] << 16);
      k2[8 + i] = k2[i];
    }
    k1[7] = 0; k1[15] = 0; k2[7] = 0; k2[15] = 0;
    uint4* d1 = (uint4*)(W1B1 + (size_t)t * 16);
    uint4* d2 = (uint4*)(W1B2 + (size_t)t * 16);
    #pragma unroll
    for (int i = 0; i < 4; i++) {
      d1[i] = make_uint4(k1[4*i], k1[4*i+1], k1[4*i+2], k1[4*i+3]);
      d2[i] = make_uint4(k2[4*i], k2[4*i+1], k2[4*i+2], k2[4*i+3]);
    }
  } else if (blk < 64) {
    int t = (blk - 48) * 256 + tid;   // 0..4095: w2T hi/lo
    int l = t >> 11, j = t & 2047;
    #pragma unroll
    for (int d = 0; d < 16; d++) {
      float v = (d < 14) ? ffw2[((size_t)l * 14 + d) * FF + j] : 0.f;
      W2h[((size_t)l * 16 + d) * FF + j] = bf_hi(v);
      W2l[((size_t)l * 16 + d) * FF + j] = bf_hi(v - bf_hi_f(v));
    }
  } else {
    int r = (blk - 64) * 256 + tid;   // 0..8191: layer-0 qkv from x
    float hr[16];
    #pragma unroll
    for (int d = 0; d < 14; d++) hr[d] = x[(size_t)r * 14 + d];
    hr[14] = 0.f; hr[15] = 0.f;
    STORE16(h + (size_t)r * DP, hr);
    qkv_compute_store(r, hr, wqkv, bqkv, Qpack, KB1, KB2, VhiT, VloT);
  }
}

// ------- MFMA attention phase 1: 512 keys/chunk; 32-row batched LDS phase -------
__global__ __launch_bounds__(256, 4) void attn_mfma(
    const unsigned int* __restrict__ Qpack, const unsigned int* __restrict__ KB1,
    const unsigned int* __restrict__ KB2, const unsigned short* __restrict__ VhiT,
    const unsigned short* __restrict__ VloT, float* __restrict__ part) {
  __shared__ float Plds[4][32][36];
  const int tid = threadIdx.x;
  const int wave = tid >> 6;
  const int lane = tid & 63;
  const int lo4 = lane & 15;
  const int hi4 = lane >> 4;
  const int qbase = blockIdx.x * 128 + wave * 32;
  const int kbase0 = blockIdx.y * 512;

  const bf16x8* Qp = (const bf16x8*)Qpack;
  const bf16x8* B1 = (const bf16x8*)KB1;
  const bf16x8* B2 = (const bf16x8*)KB2;
  const bf16x8* Vh = (const bf16x8*)VhiT;
  const bf16x8* Vl = (const bf16x8*)VloT;

  bf16x8 aQ0 = Qp[(size_t)(qbase + lo4) * 4 + hi4];
  bf16x8 aQ1 = Qp[(size_t)(qbase + 16 + lo4) * 4 + hi4];
  f32x4 acc0 = {0.f, 0.f, 0.f, 0.f};
  f32x4 acc1 = {0.f, 0.f, 0.f, 0.f};
  const f32x4 zero = {0.f, 0.f, 0.f, 0.f};

  for (int c = 0; c < 16; c++) {
    const int kb = kbase0 + c * 32;
    bf16x8 b1g0 = B1[(size_t)(kb + lo4) * 4 + hi4];
    bf16x8 b2g0 = B2[(size_t)(kb + lo4) * 4 + hi4];
    bf16x8 b1g1 = B1[(size_t)(kb + 16 + lo4) * 4 + hi4];
    bf16x8 b2g1 = B2[(size_t)(kb + 16 + lo4) * 4 + hi4];
    bf16x8 vh = Vh[(size_t)lo4 * 1024 + (kb >> 3) + hi4];
    bf16x8 vl = Vl[(size_t)lo4 * 1024 + (kb >> 3) + hi4];

    // S for both 16-row subs: 8 independent-chain MFMAs
    f32x4 s00 = __builtin_amdgcn_mfma_f32_16x16x32_bf16(aQ0, b1g0, zero, 0, 0, 0);
    f32x4 s01 = __builtin_amdgcn_mfma_f32_16x16x32_bf16(aQ0, b1g1, zero, 0, 0, 0);
    f32x4 s10 = __builtin_amdgcn_mfma_f32_16x16x32_bf16(aQ1, b1g0, zero, 0, 0, 0);
    f32x4 s11 = __builtin_amdgcn_mfma_f32_16x16x32_bf16(aQ1, b1g1, zero, 0, 0, 0);
    s00 = __builtin_amdgcn_mfma_f32_16x16x32_bf16(aQ0, b2g0, s00, 0, 0, 0);
    s01 = __builtin_amdgcn_mfma_f32_16x16x32_bf16(aQ0, b2g1, s01, 0, 0, 0);
    s10 = __builtin_amdgcn_mfma_f32_16x16x32_bf16(aQ1, b2g0, s10, 0, 0, 0);
    s11 = __builtin_amdgcn_mfma_f32_16x16x32_bf16(aQ1, b2g1, s11, 0, 0, 0);
    // one batched exp/store phase for all 32 rows
    #pragma unroll
    for (int reg = 0; reg < 4; reg++) {
      Plds[wave][hi4 * 4 + reg][lo4]           = fast_exp2(s00[reg]);
      Plds[wave][hi4 * 4 + reg][16 + lo4]      = fast_exp2(s01[reg]);
      Plds[wave][16 + hi4 * 4 + reg][lo4]      = fast_exp2(s10[reg]);
      Plds[wave][16 + hi4 * 4 + reg][16 + lo4] = fast_exp2(s11[reg]);
    }
    __asm__ volatile("s_waitcnt lgkmcnt(0)" ::: "memory");
    const float4* p0 = (const float4*)&Plds[wave][lo4][hi4 * 8];
    const float4* p1 = (const float4*)&Plds[wave][16 + lo4][hi4 * 8];
    float4 a0 = p0[0], a1 = p0[1], c0 = p1[0], c1 = p1[1];
    float pv0[8] = {a0.x, a0.y, a0.z, a0.w, a1.x, a1.y, a1.z, a1.w};
    float pv1[8] = {c0.x, c0.y, c0.z, c0.w, c1.x, c1.y, c1.z, c1.w};
    bf16x8 ph0, pl0, ph1, pl1;
    split8(pv0, &ph0, &pl0);
    split8(pv1, &ph1, &pl1);
    acc0 = __builtin_amdgcn_mfma_f32_16x16x32_bf16(ph0, vh, acc0, 0, 0, 0);
    acc1 = __builtin_amdgcn_mfma_f32_16x16x32_bf16(ph1, vh, acc1, 0, 0, 0);
    acc0 = __builtin_amdgcn_mfma_f32_16x16x32_bf16(pl0, vh, acc0, 0, 0, 0);
    acc1 = __builtin_amdgcn_mfma_f32_16x16x32_bf16(pl1, vh, acc1, 0, 0, 0);
    acc0 = __builtin_amdgcn_mfma_f32_16x16x32_bf16(ph0, vl, acc0, 0, 0, 0);
    acc1 = __builtin_amdgcn_mfma_f32_16x16x32_bf16(ph1, vl, acc1, 0, 0, 0);
    __asm__ volatile("s_waitcnt lgkmcnt(0)" ::: "memory");
  }
  float* pbase = part + (size_t)blockIdx.y * NN * 16;
  #pragma unroll
  for (int reg = 0; reg < 4; reg++) {
    int row0 = qbase + hi4 * 4 + reg;
    pbase[(size_t)row0 * 16 + lo4] = acc0[reg];
    pbase[(size_t)(row0 + 16) * 16 + lo4] = acc1[reg];
  }
}

// ---- attention combine (4 threads/row) + out-proj + residual + LN1 ----
__global__ void attn_comb_ln1(float* __restrict__ h, const float* __restrict__ part,
                              const float* __restrict__ wo, const float* __restrict__ bo,
                              const float* __restrict__ g, const float* __restrict__ b,
                              unsigned int* __restrict__ Hpack) {
  int t = blockIdx.x * 128 + threadIdx.x;
  int r = t >> 2, q = t & 3;
  float L = 0.f;
  float A[14];
  #pragma unroll
  for (int d = 0; d < 14; d++) A[d] = 0.f;
  #pragma unroll
  for (int c = q; c < NCH; c += 4) {
    float p[16];
    LOAD16(p, part + ((size_t)c * NN + r) * 16);
    L += p[14];
    #pragma unroll
    for (int d = 0; d < 14; d++) A[d] += p[d];
  }
  #pragma unroll
  for (int off = 1; off < 4; off <<= 1) {
    L += __shfl_xor(L, off, 64);
    #pragma unroll
    for (int d = 0; d < 14; d++) A[d] += __shfl_xor(A[d], off, 64);
  }
  if (q == 0) {
    float inv = 1.f / L;
    float a[14];
    #pragma unroll
    for (int d = 0; d < 14; d++) a[d] = A[d] * inv;
    float hr[16];
    LOAD16(hr, h + (size_t)r * DP);
    float xx[14];
    #pragma unroll
    for (int i = 0; i < 14; i++) {
      float s = bo[i];
      #pragma unroll
      for (int d = 0; d < 14; d++) s = fmaf(wo[i * 14 + d], a[d], s);
      xx[i] = hr[i] + s;
    }
    float mu = 0.f;
    #pragma unroll
    for (int i = 0; i < 14; i++) mu += xx[i];
    mu *= (1.f / 14.f);
    float var = 0.f;
    #pragma unroll
    for (int i = 0; i < 14; i++) { float tt = xx[i] - mu; var = fmaf(tt, tt, var); }
    var *= (1.f / 14.f);
    float rs = rsqrtf(var + LN_EPS);
    float o[16];
    #pragma unroll
    for (int i = 0; i < 14; i++) o[i] = fmaf((xx[i] - mu) * rs, g[i], b[i]);
    o[14] = 0.f; o[15] = 0.f;
    STORE16(h + (size_t)r * DP, o);
    store_apack(Hpack + (size_t)r * 16, o);
  }
}

// ------- MFMA FFN phase 1: 256 neurons/chunk; 32-row batched LDS phase -------
__global__ __launch_bounds__(256, 4) void ffn_mfma(
    const unsigned int* __restrict__ Hpack, const unsigned int* __restrict__ W1B1,
    const unsigned int* __restrict__ W1B2, const unsigned short* __restrict__ W2h,
    const unsigned short* __restrict__ W2l, const float* __restrict__ b1,
    float* __restrict__ part) {
  __shared__ float Plds[4][32][36];
  const int tid = threadIdx.x;
  const int wave = tid >> 6;
  const int lane = tid & 63;
  const int lo4 = lane & 15;
  const int hi4 = lane >> 4;
  const int qbase = blockIdx.x * 128 + wave * 32;
  const int jbase0 = blockIdx.y * 256;

  const bf16x8* Hp = (const bf16x8*)Hpack;
  const bf16x8* B1 = (const bf16x8*)W1B1;
  const bf16x8* B2 = (const bf16x8*)W1B2;
  const bf16x8* Vh = (const bf16x8*)W2h;
  const bf16x8* Vl = (const bf16x8*)W2l;

  bf16x8 aH0 = Hp[(size_t)(qbase + lo4) * 4 + hi4];
  bf16x8 aH1 = Hp[(size_t)(qbase + 16 + lo4) * 4 + hi4];
  f32x4 acc0 = {0.f, 0.f, 0.f, 0.f};
  f32x4 acc1 = {0.f, 0.f, 0.f, 0.f};
  const f32x4 zero = {0.f, 0.f, 0.f, 0.f};

  for (int c = 0; c < 8; c++) {
    const int jb = jbase0 + c * 32;
    bf16x8 b1g0 = B1[(size_t)(jb + lo4) * 4 + hi4];
    bf16x8 b2g0 = B2[(size_t)(jb + lo4) * 4 + hi4];
    bf16x8 b1g1 = B1[(size_t)(jb + 16 + lo4) * 4 + hi4];
    bf16x8 b2g1 = B2[(size_t)(jb + 16 + lo4) * 4 + hi4];
    bf16x8 vh = Vh[(size_t)lo4 * 256 + (jb >> 3) + hi4];
    bf16x8 vl = Vl[(size_t)lo4 * 256 + (jb >> 3) + hi4];
    float bb0 = b1[jb + lo4];
    float bb1 = b1[jb + 16 + lo4];

    f32x4 s00 = __builtin_amdgcn_mfma_f32_16x16x32_bf16(aH0, b1g0, zero, 0, 0, 0);
    f32x4 s01 = __builtin_amdgcn_mfma_f32_16x16x32_bf16(aH0, b1g1, zero, 0, 0, 0);
    f32x4 s10 = __builtin_amdgcn_mfma_f32_16x16x32_bf16(aH1, b1g0, zero, 0, 0, 0);
    f32x4 s11 = __builtin_amdgcn_mfma_f32_16x16x32_bf16(aH1, b1g1, zero, 0, 0, 0);
    s00 = __builtin_amdgcn_mfma_f32_16x16x32_bf16(aH0, b2g0, s00, 0, 0, 0);
    s01 = __builtin_amdgcn_mfma_f32_16x16x32_bf16(aH0, b2g1, s01, 0, 0, 0);
    s10 = __builtin_amdgcn_mfma_f32_16x16x32_bf16(aH1, b2g0, s10, 0, 0, 0);
    s11 = __builtin_amdgcn_mfma_f32_16x16x32_bf16(aH1, b2g1, s11, 0, 0, 0);
    #pragma unroll
    for (int reg = 0; reg < 4; reg++) {
      Plds[wave][hi4 * 4 + reg][lo4]           = fmaxf(s00[reg] + bb0, 0.f);
      Plds[wave][hi4 * 4 + reg][16 + lo4]      = fmaxf(s01[reg] + bb1, 0.f);
      Plds[wave][16 + hi4 * 4 + reg][lo4]      = fmaxf(s10[reg] + bb0, 0.f);
      Plds[wave][16 + hi4 * 4 + reg][16 + lo4] = fmaxf(s11[reg] + bb1, 0.f);
    }
    __asm__ volatile("s_waitcnt lgkmcnt(0)" ::: "memory");
    const float4* p0 = (const float4*)&Plds[wave][lo4][hi4 * 8];
    const float4* p1 = (const float4*)&Plds[wave][16 + lo4][hi4 * 8];
    float4 a0 = p0[0], a1 = p0[1], c0 = p1[0], c1 = p1[1];
    float pv0[8] = {a0.x, a0.y, a0.z, a0.w, a1.x, a1.y, a1.z, a1.w};
    float pv1[8] = {c0.x, c0.y, c0.z, c0.w, c1.x, c1.y, c1.z, c1.w};
    bf16x8 th0, tl0, th1, tl1;
    split8(pv0, &th0, &tl0);
    split8(pv1, &th1, &tl1);
    acc0 = __builtin_amdgcn_mfma_f32_16x16x32_bf16(th0, vh, acc0, 0, 0, 0);
    acc1 = __builtin_amdgcn_mfma_f32_16x16x32_bf16(th1, vh, acc1, 0, 0, 0);
    acc0 = __builtin_amdgcn_mfma_f32_16x16x32_bf16(tl0, vh, acc0, 0, 0, 0);
    acc1 = __builtin_amdgcn_mfma_f32_16x16x32_bf16(tl1, vh, acc1, 0, 0, 0);
    acc0 = __builtin_amdgcn_mfma_f32_16x16x32_bf16(th0, vl, acc0, 0, 0, 0);
    acc1 = __builtin_amdgcn_mfma_f32_16x16x32_bf16(th1, vl, acc1, 0, 0, 0);
    __asm__ volatile("s_waitcnt lgkmcnt(0)" ::: "memory");
  }
  float* pbase = part + (size_t)blockIdx.y * NN * 16;
  #pragma unroll
  for (int reg = 0; reg < 4; reg++) {
    int row0 = qbase + hi4 * 4 + reg;
    pbase[(size_t)row0 * 16 + lo4] = acc0[reg];
    pbase[(size_t)(row0 + 16) * 16 + lo4] = acc1[reg];
  }
}

// ---- FFN combine (4 threads/row) + residual + LN2 + next-layer qkv packs ----
__global__ void ffn_ln2_qkv(float* __restrict__ h, const float* __restrict__ part,
                            const float* __restrict__ b2, const float* __restrict__ g,
                            const float* __restrict__ b,
                            const float* __restrict__ wqkv, const float* __restrict__ bqkv,
                            unsigned int* __restrict__ Qpack,
                            unsigned int* __restrict__ KB1, unsigned int* __restrict__ KB2,
                            unsigned short* __restrict__ VhiT,
                            unsigned short* __restrict__ VloT) {
  int t = blockIdx.x * 128 + threadIdx.x;
  int r = t >> 2, q = t & 3;
  float f[14];
  #pragma unroll
  for (int d = 0; d < 14; d++) f[d] = 0.f;
  #pragma unroll
  for (int c = q; c < NFCH; c += 4) {
    float p[16];
    LOAD16(p, part + ((size_t)c * NN + r) * 16);
    #pragma unroll
    for (int d = 0; d < 14; d++) f[d] += p[d];
  }
  #pragma unroll
  for (int off = 1; off < 4; off <<= 1) {
    #pragma unroll
    for (int d = 0; d < 14; d++) f[d] += __shfl_xor(f[d], off, 64);
  }
  if (q == 0) {
    float hr[16];
    LOAD16(hr, h + (size_t)r * DP);
    float xx[14];
    #pragma unroll
    for (int i = 0; i < 14; i++) xx[i] = hr[i] + f[i] + b2[i];
    float mu = 0.f;
    #pragma unroll
    for (int i = 0; i < 14; i++) mu += xx[i];
    mu *= (1.f / 14.f);
    float var = 0.f;
    #pragma unroll
    for (int i = 0; i < 14; i++) { float tt = xx[i] - mu; var = fmaf(tt, tt, var); }
    var *= (1.f / 14.f);
    float rs = rsqrtf(var + LN_EPS);
    float o[16];
    #pragma unroll
    for (int i = 0; i < 14; i++) o[i] = fmaf((xx[i] - mu) * rs, g[i], b[i]);
    o[14] = 0.f; o[15] = 0.f;
    STORE16(h + (size_t)r * DP, o);
    qkv_compute_store(r, o, wqkv, bqkv, Qpack, KB1, KB2, VhiT, VloT);
  }
}

// ---- fused tail: FFN combine + LN2 + size head + regression head (16 rows/block) ----
__global__ __launch_bounds__(256, 4) void tail_fused(
    const float* __restrict__ h, const float* __restrict__ part,
    const float* __restrict__ b2, const float* __restrict__ g, const float* __restrict__ b,
    const float* __restrict__ fc1w, const float* __restrict__ fc1b,
    const float* __restrict__ fc2w, const float* __restrict__ fc2b,
    const float* __restrict__ x, const float* __restrict__ y,
    const unsigned short* __restrict__ B3h, const unsigned short* __restrict__ B3l,
    const float* __restrict__ b3,
    const unsigned short* __restrict__ B4h, const unsigned short* __restrict__ B4l,
    const float* __restrict__ b4,
    const float* __restrict__ w5, const float* __restrict__ b5,
    float* __restrict__ out, float* __restrict__ outr) {
  __shared__ alignas(16) unsigned short Ah[16][72], Al[16][72];
  __shared__ alignas(16) unsigned short R1h[16][264], R1l[16][264];
  __shared__ float sred[4][16][16];
  __shared__ float szf[16];
  const int tid = threadIdx.x;
  const int wave = tid >> 6;
  const int lane = tid & 63;
  const int lo4 = lane & 15;
  const int hi4 = lane >> 4;
  const int rbase = blockIdx.x * 16;

  // phase A: ffn combine + LN2 + size head for this block's 16 rows
  if (tid < 128) {
    int m = tid >> 3, c = tid & 7;
    int r = rbase + m;
    float p[16];
    LOAD16(p, part + ((size_t)c * NN + r) * 16);
    float f[14];
    #pragma unroll
    for (int d = 0; d < 14; d++) f[d] = p[d];
    #pragma unroll
    for (int off = 1; off < 8; off <<= 1) {
      #pragma unroll
      for (int d = 0; d < 14; d++) f[d] += __shfl_xor(f[d], off, 64);
    }
    if (c == 0) {
      float hr[16];
      LOAD16(hr, h + (size_t)r * DP);
      float xx[14];
      #pragma unroll
      for (int i = 0; i < 14; i++) xx[i] = hr[i] + f[i] + b2[i];
      float mu = 0.f;
      #pragma unroll
      for (int i = 0; i < 14; i++) mu += xx[i];
      mu *= (1.f / 14.f);
      float var = 0.f;
      #pragma unroll
      for (int i = 0; i < 14; i++) { float tt = xx[i] - mu; var = fmaf(tt, tt, var); }
      var *= (1.f / 14.f);
      float rs = rsqrtf(var + LN_EPS);
      float o[14];
      #pragma unroll
      for (int i = 0; i < 14; i++) o[i] = fmaf((xx[i] - mu) * rs, g[i], b[i]);
      float s = fc2b[0];
      #pragma unroll
      for (int i = 0; i < 14; i++) {
        float tt = fc1b[i];
        #pragma unroll
        for (int d = 0; d < 14; d++) tt = fmaf(fc1w[i * 14 + d], o[d], tt);
        s = fmaf(tt, fc2w[i], s);
      }
      out[r] = s;
      int si = (int)s;  // trunc toward zero, matches astype(int32)
      szf[m] = (float)si;
    }
  }
  __syncthreads();

  // phase B: stage reg_in -> bf16 hi/lo in LDS (k >= 51 zero)
  for (int idx = tid; idx < 16 * 64; idx += 256) {
    int m = idx >> 6, k = idx & 63;
    int r = rbase + m;
    float v = 0.f;
    if (k == 0)       v = szf[m];
    else if (k < 15)  v = x[(size_t)r * 14 + (k - 1)];
    else if (k < 51)  v = y[(size_t)r * 36 + (k - 15)];
    Ah[m][k] = bf_hi(v);
    Al[m][k] = bf_hi(v - bf_hi_f(v));
  }
  __syncthreads();

  const f32x4 zero = {0.f, 0.f, 0.f, 0.f};
  f32x4 acc[4];
  #pragma unroll
  for (int nt = 0; nt < 4; nt++) acc[nt] = zero;

  #pragma unroll
  for (int ks = 0; ks < 2; ks++) {
    bf16x8 ah = *(const bf16x8*)&Ah[lo4][ks * 32 + hi4 * 8];
    bf16x8 al = *(const bf16x8*)&Al[lo4][ks * 32 + hi4 * 8];
    #pragma unroll
    for (int nt = 0; nt < 4; nt++) {
      int fi = ((wave * 4 + nt) * 2 + ks) * 64 + lane;
      bf16x8 bh = ((const bf16x8*)B3h)[fi];
      bf16x8 bl = ((const bf16x8*)B3l)[fi];
      acc[nt] = __builtin_amdgcn_mfma_f32_16x16x32_bf16(ah, bh, acc[nt], 0, 0, 0);
      acc[nt] = __builtin_amdgcn_mfma_f32_16x16x32_bf16(al, bh, acc[nt], 0, 0, 0);
      acc[nt] = __builtin_amdgcn_mfma_f32_16x16x32_bf16(ah, bl, acc[nt], 0, 0, 0);
    }
  }
  #pragma unroll
  for (int nt = 0; nt < 4; nt++) {
    int n = (wave * 4 + nt) * 16 + lo4;
    float bb = b3[n];
    #pragma unroll
    for (int reg = 0; reg < 4; reg++) {
      int m = hi4 * 4 + reg;
      float v = fmaxf(acc[nt][reg] + bb, 0.f);
      R1h[m][n] = bf_hi(v);
      R1l[m][n] = bf_hi(v - bf_hi_f(v));
    }
  }
  __syncthreads();

  #pragma unroll
  for (int nt = 0; nt < 4; nt++) acc[nt] = zero;
  #pragma unroll
  for (int ks = 0; ks < 8; ks++) {
    bf16x8 ah = *(const bf16x8*)&R1h[lo4][ks * 32 + hi4 * 8];
    bf16x8 al = *(const bf16x8*)&R1l[lo4][ks * 32 + hi4 * 8];
    #pragma unroll
    for (int nt = 0; nt < 4; nt++) {
      int fi = ((wave * 4 + nt) * 8 + ks) * 64 + lane;
      bf16x8 bh = ((const bf16x8*)B4h)[fi];
      bf16x8 bl = ((const bf16x8*)B4l)[fi];
      acc[nt] = __builtin_amdgcn_mfma_f32_16x16x32_bf16(ah, bh, acc[nt], 0, 0, 0);
      acc[nt] = __builtin_amdgcn_mfma_f32_16x16x32_bf16(al, bh, acc[nt], 0, 0, 0);
      acc[nt] = __builtin_amdgcn_mfma_f32_16x16x32_bf16(ah, bl, acc[nt], 0, 0, 0);
    }
  }
  float s[4] = {0.f, 0.f, 0.f, 0.f};
  #pragma unroll
  for (int nt = 0; nt < 4; nt++) {
    int n = (wave * 4 + nt) * 16 + lo4;
    float bb = b4[n], ww = w5[n];
    #pragma unroll
    for (int reg = 0; reg < 4; reg++)
      s[reg] = fmaf(fmaxf(acc[nt][reg] + bb, 0.f), ww, s[reg]);
  }
  #pragma unroll
  for (int reg = 0; reg < 4; reg++) sred[wave][hi4 * 4 + reg][lo4] = s[reg];
  __syncthreads();

  if (tid < 16) {
    float t = b5[0];
    #pragma unroll
    for (int w = 0; w < 4; w++) {
      const float4* p = (const float4*)&sred[w][tid][0];
      float4 a0 = p[0], a1 = p[1], a2 = p[2], a3 = p[3];
      t += ((a0.x + a0.y) + (a0.z + a0.w)) + ((a1.x + a1.y) + (a1.z + a1.w)) +
           ((a2.x + a2.y) + (a2.z + a2.w)) + ((a3.x + a3.y) + (a3.z + a3.w));
    }
    float sz = szf[tid];
    outr[rbase + tid] = (sz != 0.f) ? t : 0.f;
  }
}

extern "C" void kernel_launch(void* const* d_in, const int* in_sizes, int n_in,
                              void* d_out, int out_size, void* d_ws, size_t ws_size,
                              hipStream_t stream) {
  const float* x    = (const float*)d_in[0];
  const float* y    = (const float*)d_in[1];
  const float* wqkv = (const float*)d_in[2];
  const float* bqkv = (const float*)d_in[3];
  const float* wo   = (const float*)d_in[4];
  const float* bo   = (const float*)d_in[5];
  const float* ln1g = (const float*)d_in[6];
  const float* ln1b = (const float*)d_in[7];
  const float* ffw1 = (const float*)d_in[8];
  const float* ffb1 = (const float*)d_in[9];
  const float* ffw2 = (const float*)d_in[10];
  const float* ffb2 = (const float*)d_in[11];
  const float* ln2g = (const float*)d_in[12];
  const float* ln2b = (const float*)d_in[13];
  const float* fc1w = (const float*)d_in[14];
  const float* fc1b = (const float*)d_in[15];
  const float* fc2w = (const float*)d_in[16];
  const float* fc2b = (const float*)d_in[17];
  const float* fc3w = (const float*)d_in[18];
  const float* fc3b = (const float*)d_in[19];
  const float* fc4w = (const float*)d_in[20];
  const float* fc4b = (const float*)d_in[21];
  const float* fc5w = (const float*)d_in[22];
  const float* fc5b = (const float*)d_in[23];

  float* ws = (float*)d_ws;
  float*          h     = ws;                               // 131072
  unsigned int*   Qpack = (unsigned int*)(ws + 131072);     // 131072
  unsigned int*   KB1   = (unsigned int*)(ws + 262144);     // 131072
  unsigned int*   KB2   = (unsigned int*)(ws + 393216);     // 131072
  unsigned short* VhiT  = (unsigned short*)(ws + 524288);   // 65536 f
  unsigned short* VloT  = (unsigned short*)(ws + 589824);   // 65536 f
  unsigned int*   Hpack = (unsigned int*)(ws + 655360);     // 131072
  float*          part  = ws + 786432;                      // 16*8192*16 = 2097152
  unsigned short* B3h   = (unsigned short*)(ws + 2891776);  // 8192 f
  unsigned short* B3l   = (unsigned short*)(ws + 2899968);
  unsigned short* B4h   = (unsigned short*)(ws + 2908160);  // 32768 f
  unsigned short* B4l   = (unsigned short*)(ws + 2940928);
  unsigned int*   W1B1  = (unsigned int*)(ws + 2973696);    // 65536
  unsigned int*   W1B2  = (unsigned int*)(ws + 3039232);
  unsigned short* W2h   = (unsigned short*)(ws + 3104768);  // 32768 f
  unsigned short* W2l   = (unsigned short*)(ws + 3137536);

  float* out = (float*)d_out;

  pack_all<<<96, 256, 0, stream>>>(fc3w, fc4w, ffw1, ffw2, x, wqkv, bqkv, h,
                                   Qpack, KB1, KB2, VhiT, VloT,
                                   B3h, B3l, B4h, B4l, W1B1, W1B2, W2h, W2l);
  for (int l = 0; l < 2; l++) {
    attn_mfma<<<dim3(64, NCH), 256, 0, stream>>>(Qpack, KB1, KB2, VhiT, VloT, part);
    attn_comb_ln1<<<256, 128, 0, stream>>>(h, part, wo + (size_t)l * 196,
                                           bo + (size_t)l * 14, ln1g + (size_t)l * 14,
                                           ln1b + (size_t)l * 14, Hpack);
    ffn_mfma<<<dim3(64, NFCH), 256, 0, stream>>>(
        Hpack, W1B1 + (size_t)l * 2048 * 16, W1B2 + (size_t)l * 2048 * 16,
        W2h + (size_t)l * 16 * FF, W2l + (size_t)l * 16 * FF,
        ffb1 + (size_t)l * FF, part);
    if (l == 0) {
      ffn_ln2_qkv<<<256, 128, 0, stream>>>(h, part, ffb2, ln2g, ln2b,
                                           wqkv + 42 * 14, bqkv + 42,
                                           Qpack, KB1, KB2, VhiT, VloT);
    }
  }
  tail_fused<<<512, 256, 0, stream>>>(h, part, ffb2 + 14, ln2g + 14, ln2b + 14,
                                      fc1w, fc1b, fc2w, fc2b, x, y,
                                      B3h, B3l, fc3b, B4h, B4l, fc4b,
                                      fc5w, fc5b, out, out + NN);
}